// Round 1
// baseline (2420.088 us; speedup 1.0000x reference)
//
#include <hip/hip_runtime.h>
#include <math.h>

#define HW 3136
#define CC 256
#define TT 16

// ---------------- generic weight transpose: out[c*R + r] = in[r*C + c] ----------------
__global__ void transpose_k(const float* __restrict__ in, float* __restrict__ out, int R, int Cc) {
    int i = blockIdx.x * 256 + threadIdx.x;
    if (i < R * Cc) {
        int r = i / Cc, c = i % Cc;
        out[(size_t)c * R + r] = in[i];
    }
}

// ---------------- embed: y = LN(pe_w @ x + pe_b) for x1 and x2 ----------------
__global__ __launch_bounds__(256) void embed_k(
    const float* __restrict__ x1, const float* __restrict__ x2,
    const float* __restrict__ pe_wT, const float* __restrict__ pe_b,
    const float* __restrict__ lnw, const float* __restrict__ lnb,
    float* __restrict__ y1, float* __restrict__ y2) {
    __shared__ float xa[TT][CC];
    __shared__ float yt[TT][CC];
    const float* x = blockIdx.y ? x2 : x1;
    float* y = blockIdx.y ? y2 : y1;
    const int tid = threadIdx.x;
    const int p0 = blockIdx.x * TT;
    const int b = p0 / HW, hw0 = p0 % HW;
    const float* xb = x + (size_t)b * CC * HW + hw0;
    {   // stage x tile: xa[t][c] = x[b, c, hw0+t]
        const int tt = tid & 15, cg = tid >> 4;
        for (int cb = 0; cb < CC; cb += 16)
            xa[tt][cb + cg] = xb[(size_t)(cb + cg) * HW + tt];
    }
    __syncthreads();
    const int d = tid;
    float acc[TT];
#pragma unroll
    for (int t = 0; t < TT; ++t) acc[t] = pe_b[d];
    for (int c0 = 0; c0 < CC; c0 += 8) {
        float w[8];
#pragma unroll
        for (int cc = 0; cc < 8; ++cc) w[cc] = pe_wT[(size_t)(c0 + cc) * CC + d];
#pragma unroll
        for (int t = 0; t < TT; ++t) {
            const float4 a0 = *(const float4*)&xa[t][c0];
            const float4 a1 = *(const float4*)&xa[t][c0 + 4];
            acc[t] += a0.x * w[0] + a0.y * w[1] + a0.z * w[2] + a0.w * w[3]
                    + a1.x * w[4] + a1.y * w[5] + a1.z * w[6] + a1.w * w[7];
        }
    }
#pragma unroll
    for (int t = 0; t < TT; ++t) yt[t][d] = acc[t];
    __syncthreads();
    // LayerNorm per token: one wave handles 4 tokens
    const int wave = tid >> 6, lane = tid & 63;
    for (int t = wave * 4; t < wave * 4 + 4; ++t) {
        float s = 0.f, sq = 0.f;
#pragma unroll
        for (int k = 0; k < 4; ++k) { float v = yt[t][lane + 64 * k]; s += v; sq += v * v; }
#pragma unroll
        for (int off = 32; off; off >>= 1) { s += __shfl_xor(s, off); sq += __shfl_xor(sq, off); }
        const float mean = s * (1.f / 256.f);
        const float var = sq * (1.f / 256.f) - mean * mean;
        const float rstd = rsqrtf(var + 1e-5f);
        float* yrow = y + (size_t)(p0 + t) * CC;
#pragma unroll
        for (int k = 0; k < 4; ++k) {
            const int dd = lane + 64 * k;
            yrow[dd] = (yt[t][dd] - mean) * rstd * lnw[dd] + lnb[dd];
        }
    }
}

// ---------------- n1-LN + q/k/v projection, window-ordered output ----------------
__global__ __launch_bounds__(256) void qkv_k(
    const float* __restrict__ y, const float* __restrict__ y2,
    const float* __restrict__ n1w, const float* __restrict__ n1b,
    const float* __restrict__ q_wT, const float* __restrict__ q_b,
    const float* __restrict__ kv_wT, const float* __restrict__ kv_b,
    float* __restrict__ qo, float* __restrict__ ko, float* __restrict__ vo) {
    __shared__ float a1[TT][CC];
    __shared__ float a2[TT][CC];
    const int tid = threadIdx.x;
    const int p0 = blockIdx.x * TT;
    float* f1 = &a1[0][0];
    float* f2 = &a2[0][0];
    for (int idx = tid; idx < TT * CC; idx += 256) {
        f1[idx] = y[(size_t)p0 * CC + idx];
        f2[idx] = y2[(size_t)p0 * CC + idx];
    }
    __syncthreads();
    const int wave = tid >> 6, lane = tid & 63;
    for (int t = wave * 4; t < wave * 4 + 4; ++t) {
        float s1 = 0.f, q1 = 0.f, s2 = 0.f, q2 = 0.f;
#pragma unroll
        for (int k = 0; k < 4; ++k) {
            float v1 = a1[t][lane + 64 * k]; s1 += v1; q1 += v1 * v1;
            float v2 = a2[t][lane + 64 * k]; s2 += v2; q2 += v2 * v2;
        }
#pragma unroll
        for (int off = 32; off; off >>= 1) {
            s1 += __shfl_xor(s1, off); q1 += __shfl_xor(q1, off);
            s2 += __shfl_xor(s2, off); q2 += __shfl_xor(q2, off);
        }
        const float m1 = s1 * (1.f / 256.f), m2 = s2 * (1.f / 256.f);
        const float r1 = rsqrtf(q1 * (1.f / 256.f) - m1 * m1 + 1e-5f);
        const float r2 = rsqrtf(q2 * (1.f / 256.f) - m2 * m2 + 1e-5f);
#pragma unroll
        for (int k = 0; k < 4; ++k) {
            const int dd = lane + 64 * k;
            a1[t][dd] = (a1[t][dd] - m1) * r1 * n1w[dd] + n1b[dd];
            a2[t][dd] = (a2[t][dd] - m2) * r2 * n1w[dd] + n1b[dd];
        }
    }
    __syncthreads();
    const int d = tid;
    float accq[TT], acck[TT], accv[TT];
#pragma unroll
    for (int t = 0; t < TT; ++t) { accq[t] = q_b[d]; acck[t] = kv_b[d]; accv[t] = kv_b[CC + d]; }
    for (int c0 = 0; c0 < CC; c0 += 4) {
        float wq[4], wk[4], wv[4];
#pragma unroll
        for (int cc = 0; cc < 4; ++cc) {
            wq[cc] = q_wT[(size_t)(c0 + cc) * CC + d];
            wk[cc] = kv_wT[(size_t)(c0 + cc) * 512 + d];
            wv[cc] = kv_wT[(size_t)(c0 + cc) * 512 + CC + d];
        }
#pragma unroll
        for (int t = 0; t < TT; ++t) {
            const float4 v1 = *(const float4*)&a1[t][c0];
            const float4 v2 = *(const float4*)&a2[t][c0];
            accq[t] += v1.x * wq[0] + v1.y * wq[1] + v1.z * wq[2] + v1.w * wq[3];
            acck[t] += v2.x * wk[0] + v2.y * wk[1] + v2.z * wk[2] + v2.w * wk[3];
            accv[t] += v2.x * wv[0] + v2.y * wv[1] + v2.z * wv[2] + v2.w * wv[3];
        }
    }
    for (int t = 0; t < TT; ++t) {
        const int p = p0 + t;
        const int b = p / HW, hw = p % HW;
        const int h = hw / 56, w = hw % 56;
        const int win = b * 64 + (h / 7) * 8 + (w / 7);
        const int n = (h % 7) * 7 + (w % 7);
        const size_t base = ((size_t)win * 49 + n) * CC;
        qo[base + d] = accq[t];
        ko[base + d] = acck[t];
        vo[base + d] = accv[t];
    }
}

// ---------------- attention per (window, head) ----------------
__global__ __launch_bounds__(64) void attn_k(
    const float* __restrict__ q, const float* __restrict__ k, const float* __restrict__ v,
    const float* __restrict__ rel_bias, float* __restrict__ o) {
    __shared__ float kt[49][32];
    __shared__ float vt[49][32];
    __shared__ float bs[169];
    const int win = blockIdx.x, head = blockIdx.y;
    const int lane = threadIdx.x;
    const size_t wbase = (size_t)win * 49 * CC + head * 32;
    for (int idx = lane; idx < 49 * 32; idx += 64) {
        const int j = idx >> 5, hd = idx & 31;
        kt[j][hd] = k[wbase + (size_t)j * CC + hd];
        vt[j][hd] = v[wbase + (size_t)j * CC + hd];
    }
    for (int idx = lane; idx < 169; idx += 64) bs[idx] = rel_bias[idx * 8 + head];
    __syncthreads();
    if (lane < 49) {
        const float scale = 0.17677669529663687f; // 1/sqrt(32)
        float qr[32];
#pragma unroll
        for (int hd = 0; hd < 32; ++hd) qr[hd] = q[wbase + (size_t)lane * CC + hd] * scale;
        float s[49];
        float mx = -1e30f;
        const int yi = lane / 7, xi = lane % 7;
        for (int j = 0; j < 49; ++j) {
            float dot = 0.f;
#pragma unroll
            for (int hd = 0; hd < 32; ++hd) dot += qr[hd] * kt[j][hd];
            dot += bs[(yi - j / 7 + 6) * 13 + (xi - j % 7 + 6)];
            s[j] = dot;
            mx = fmaxf(mx, dot);
        }
        float denom = 0.f;
        for (int j = 0; j < 49; ++j) { s[j] = __expf(s[j] - mx); denom += s[j]; }
        const float inv = 1.f / denom;
        const int b = win >> 6, wloc = win & 63;
        const int h = (wloc >> 3) * 7 + yi;
        const int w = (wloc & 7) * 7 + xi;
        float* orow = o + ((size_t)b * HW + h * 56 + w) * CC + head * 32;
#pragma unroll 4
        for (int hd = 0; hd < 32; ++hd) {
            float acc = 0.f;
            for (int j = 0; j < 49; ++j) acc += s[j] * vt[j][hd];
            orow[hd] = acc * inv;
        }
    }
}

// ---------------- proj + residual (in-place on y) ----------------
__global__ __launch_bounds__(256) void proj_k(
    const float* __restrict__ oin, const float* __restrict__ proj_wT,
    const float* __restrict__ proj_b, float* __restrict__ y) {
    __shared__ float a[TT][CC];
    const int tid = threadIdx.x;
    const int p0 = blockIdx.x * TT;
    float* fa = &a[0][0];
    for (int idx = tid; idx < TT * CC; idx += 256) fa[idx] = oin[(size_t)p0 * CC + idx];
    __syncthreads();
    const int d = tid;
    float acc[TT];
#pragma unroll
    for (int t = 0; t < TT; ++t) acc[t] = proj_b[d];
    for (int c0 = 0; c0 < CC; c0 += 8) {
        float w[8];
#pragma unroll
        for (int cc = 0; cc < 8; ++cc) w[cc] = proj_wT[(size_t)(c0 + cc) * CC + d];
#pragma unroll
        for (int t = 0; t < TT; ++t) {
            const float4 a0 = *(const float4*)&a[t][c0];
            const float4 a1 = *(const float4*)&a[t][c0 + 4];
            acc[t] += a0.x * w[0] + a0.y * w[1] + a0.z * w[2] + a0.w * w[3]
                    + a1.x * w[4] + a1.y * w[5] + a1.z * w[6] + a1.w * w[7];
        }
    }
    for (int t = 0; t < TT; ++t) {
        const size_t idx = (size_t)(p0 + t) * CC + d;
        y[idx] += acc[t];
    }
}

// ---------------- n2-LN + fc1 + GELU + fc2 + residual + NCHW output ----------------
__global__ __launch_bounds__(256) void mlp_k(
    const float* __restrict__ y, const float* __restrict__ n2w, const float* __restrict__ n2b,
    const float* __restrict__ fc1_wT, const float* __restrict__ fc1_b,
    const float* __restrict__ fc2_wT, const float* __restrict__ fc2_b,
    float* __restrict__ out) {
    __shared__ float ytile[TT][CC];   // raw y (residual)
    __shared__ float at[TT][CC];      // LN'd
    __shared__ float ht[TT][CC];      // h chunk, transposed [t][m_local]
    const int tid = threadIdx.x;
    const int p0 = blockIdx.x * TT;
    float* fy = &ytile[0][0];
    for (int idx = tid; idx < TT * CC; idx += 256) fy[idx] = y[(size_t)p0 * CC + idx];
    __syncthreads();
    const int wave = tid >> 6, lane = tid & 63;
    for (int t = wave * 4; t < wave * 4 + 4; ++t) {
        float s = 0.f, sq = 0.f;
#pragma unroll
        for (int k = 0; k < 4; ++k) { float v = ytile[t][lane + 64 * k]; s += v; sq += v * v; }
#pragma unroll
        for (int off = 32; off; off >>= 1) { s += __shfl_xor(s, off); sq += __shfl_xor(sq, off); }
        const float mean = s * (1.f / 256.f);
        const float rstd = rsqrtf(sq * (1.f / 256.f) - mean * mean + 1e-5f);
#pragma unroll
        for (int k = 0; k < 4; ++k) {
            const int dd = lane + 64 * k;
            at[t][dd] = (ytile[t][dd] - mean) * rstd * n2w[dd] + n2b[dd];
        }
    }
    __syncthreads();
    const int d = tid;
    float acc2[TT];
#pragma unroll
    for (int t = 0; t < TT; ++t) acc2[t] = fc2_b[d];
    for (int mc = 0; mc < 4; ++mc) {
        const int m = mc * 256 + d;
        float hm[TT];
#pragma unroll
        for (int t = 0; t < TT; ++t) hm[t] = fc1_b[m];
        for (int c0 = 0; c0 < CC; c0 += 8) {
            float w[8];
#pragma unroll
            for (int cc = 0; cc < 8; ++cc) w[cc] = fc1_wT[(size_t)(c0 + cc) * 1024 + m];
#pragma unroll
            for (int t = 0; t < TT; ++t) {
                const float4 a0 = *(const float4*)&at[t][c0];
                const float4 a1 = *(const float4*)&at[t][c0 + 4];
                hm[t] += a0.x * w[0] + a0.y * w[1] + a0.z * w[2] + a0.w * w[3]
                       + a1.x * w[4] + a1.y * w[5] + a1.z * w[6] + a1.w * w[7];
            }
        }
#pragma unroll
        for (int t = 0; t < TT; ++t) {
            const float xv = hm[t];
            hm[t] = 0.5f * xv * (1.f + erff(xv * 0.70710678118654752f));
        }
        __syncthreads();   // prior chunk's readers done
#pragma unroll
        for (int t = 0; t < TT; ++t) ht[t][d] = hm[t];
        __syncthreads();
        for (int m0 = 0; m0 < 256; m0 += 8) {
            float w2[8];
#pragma unroll
            for (int cc = 0; cc < 8; ++cc) w2[cc] = fc2_wT[(size_t)(mc * 256 + m0 + cc) * CC + d];
#pragma unroll
            for (int t = 0; t < TT; ++t) {
                const float4 h0 = *(const float4*)&ht[t][m0];
                const float4 h1 = *(const float4*)&ht[t][m0 + 4];
                acc2[t] += h0.x * w2[0] + h0.y * w2[1] + h0.z * w2[2] + h0.w * w2[3]
                         + h1.x * w2[4] + h1.y * w2[5] + h1.z * w2[6] + h1.w * w2[7];
            }
        }
    }
    for (int t = 0; t < TT; ++t) {
        const int p = p0 + t;
        const int b = p / HW, hw = p % HW;
        out[((size_t)b * CC + d) * HW + hw] = ytile[t][d] + acc2[t];
    }
}

extern "C" void kernel_launch(void* const* d_in, const int* in_sizes, int n_in,
                              void* d_out, int out_size, void* d_ws, size_t ws_size,
                              hipStream_t stream) {
    const float* x1      = (const float*)d_in[0];
    const float* x2      = (const float*)d_in[1];
    const float* pe_w    = (const float*)d_in[2];
    const float* pe_b    = (const float*)d_in[3];
    const float* pe_ln_w = (const float*)d_in[4];
    const float* pe_ln_b = (const float*)d_in[5];
    const float* n1_w    = (const float*)d_in[6];
    const float* n1_b    = (const float*)d_in[7];
    const float* q_w     = (const float*)d_in[8];
    const float* q_b     = (const float*)d_in[9];
    const float* kv_w    = (const float*)d_in[10];
    const float* kv_b    = (const float*)d_in[11];
    const float* rel_bias= (const float*)d_in[12];
    const float* proj_w  = (const float*)d_in[13];
    const float* proj_b  = (const float*)d_in[14];
    const float* n2_w    = (const float*)d_in[15];
    const float* n2_b    = (const float*)d_in[16];
    const float* fc1_w   = (const float*)d_in[17];
    const float* fc1_b   = (const float*)d_in[18];
    const float* fc2_w   = (const float*)d_in[19];
    const float* fc2_b   = (const float*)d_in[20];
    float* out = (float*)d_out;

    float* ws = (float*)d_ws;
    const size_t NTOK = 50176;
    float* buf_y  = ws;
    float* buf_y2 = buf_y  + NTOK * 256;  // later reused for attention output o
    float* buf_q  = buf_y2 + NTOK * 256;
    float* buf_k  = buf_q  + NTOK * 256;
    float* buf_v  = buf_k  + NTOK * 256;
    float* w_pe   = buf_v  + NTOK * 256;
    float* w_q    = w_pe   + 65536;
    float* w_kv   = w_q    + 65536;
    float* w_proj = w_kv   + 131072;
    float* w_fc1  = w_proj + 65536;
    float* w_fc2  = w_fc1  + 262144;

    transpose_k<<<(65536 + 255) / 256, 256, 0, stream>>>(pe_w, w_pe, 256, 256);
    transpose_k<<<(65536 + 255) / 256, 256, 0, stream>>>(q_w, w_q, 256, 256);
    transpose_k<<<(131072 + 255) / 256, 256, 0, stream>>>(kv_w, w_kv, 512, 256);
    transpose_k<<<(65536 + 255) / 256, 256, 0, stream>>>(proj_w, w_proj, 256, 256);
    transpose_k<<<(262144 + 255) / 256, 256, 0, stream>>>(fc1_w, w_fc1, 1024, 256);
    transpose_k<<<(262144 + 255) / 256, 256, 0, stream>>>(fc2_w, w_fc2, 256, 1024);

    embed_k<<<dim3(3136, 2), 256, 0, stream>>>(x1, x2, w_pe, pe_b, pe_ln_w, pe_ln_b, buf_y, buf_y2);
    qkv_k<<<3136, 256, 0, stream>>>(buf_y, buf_y2, n1_w, n1_b, w_q, q_b, w_kv, kv_b, buf_q, buf_k, buf_v);
    attn_k<<<dim3(1024, 8), 64, 0, stream>>>(buf_q, buf_k, buf_v, rel_bias, buf_y2);
    proj_k<<<3136, 256, 0, stream>>>(buf_y2, w_proj, proj_b, buf_y);
    mlp_k<<<3136, 256, 0, stream>>>(buf_y, n2_w, n2_b, w_fc1, fc1_b, w_fc2, fc2_b, out);
}

// Round 3
// 1233.155 us; speedup vs baseline: 1.9625x; 1.9625x over previous
//
#include <hip/hip_runtime.h>
#include <math.h>

#define HW 3136
typedef unsigned short u16;
typedef unsigned int u32;
typedef __attribute__((ext_vector_type(8))) short bfrag;   // 8 bf16 (4 VGPRs)
typedef __attribute__((ext_vector_type(4))) float f32x4;   // MFMA accumulator

#define MFMA16(A, B, C) __builtin_amdgcn_mfma_f32_16x16x32_bf16(A, B, C, 0, 0, 0)

__device__ __forceinline__ u16 f2bf(float f) {            // RNE float->bf16
    u32 u = __builtin_bit_cast(u32, f);
    u = (u + 0x7fffu + ((u >> 16) & 1u)) >> 16;
    return (u16)u;
}
__device__ __forceinline__ float bflo(u32 v) { return __builtin_bit_cast(float, v << 16); }
__device__ __forceinline__ float bfhi(u32 v) { return __builtin_bit_cast(float, v & 0xffff0000u); }

// ---- pack W [N][K] fp32 (row-major, as given) into MFMA fragment order ----
// tile = kt*NT + jt ; lane holds 8 consecutive k at row/col (lane%16), kgroup (lane/16)
__global__ void pack_k(const float* __restrict__ W, u16* __restrict__ out, int K, int NT) {
    const int tile = blockIdx.x, l = threadIdx.x;
    const int kt = tile / NT, jt = tile % NT;
    const int n = jt * 16 + (l & 15);
    const int k0 = kt * 32 + (l >> 4) * 8;
    const float* src = W + (size_t)n * K + k0;
    float4 s0 = *(const float4*)src;
    float4 s1 = *(const float4*)(src + 4);
    uint4 u;
    u.x = (u32)f2bf(s0.x) | ((u32)f2bf(s0.y) << 16);
    u.y = (u32)f2bf(s0.z) | ((u32)f2bf(s0.w) << 16);
    u.z = (u32)f2bf(s1.x) | ((u32)f2bf(s1.y) << 16);
    u.w = (u32)f2bf(s1.z) | ((u32)f2bf(s1.w) << 16);
    *(uint4*)(out + ((size_t)tile * 64 + l) * 8) = u;
}

// ---- embed: y = LN(pe_w @ x + pe_b); A-fragments gathered straight from NCHW x ----
__global__ __launch_bounds__(256) void embed_k(
    const float* __restrict__ x1, const float* __restrict__ x2,
    const u16* __restrict__ wp, const float* __restrict__ pe_b,
    const float* __restrict__ lnw, const float* __restrict__ lnb,
    float* __restrict__ y1, float* __restrict__ y2) {
    const float* x = blockIdx.y ? x2 : x1;
    float* y = blockIdx.y ? y2 : y1;
    const int tid = threadIdx.x, w = tid >> 6, l = tid & 63;
    const int lj = l & 15, lg = l >> 4;
    const int blk = blockIdx.x, b = blk / 49;
    const int hw0 = (blk % 49) * 64 + w * 16;     // wave's 16 tokens
    const float* xb = x + (size_t)b * 256 * HW + hw0 + lj;
    bfrag af[8];
#pragma unroll
    for (int kt = 0; kt < 8; ++kt)
#pragma unroll
        for (int bb = 0; bb < 8; ++bb)
            af[kt][bb] = (short)f2bf(xb[(size_t)(kt * 32 + lg * 8 + bb) * HW]);
    f32x4 acc[16];
#pragma unroll
    for (int jt = 0; jt < 16; ++jt) { float bb = pe_b[jt * 16 + lj]; f32x4 t = {bb, bb, bb, bb}; acc[jt] = t; }
#pragma unroll
    for (int jt = 0; jt < 16; ++jt)
#pragma unroll
        for (int kt = 0; kt < 8; ++kt)
            acc[jt] = MFMA16(af[kt], *(const bfrag*)(wp + (size_t)((kt * 16 + jt) * 64 + l) * 8), acc[jt]);
    // LayerNorm: token row = 4*lg + r lives in this lane's 16-lane group
    float sum[4] = {0, 0, 0, 0}, sq[4] = {0, 0, 0, 0};
#pragma unroll
    for (int jt = 0; jt < 16; ++jt)
#pragma unroll
        for (int r = 0; r < 4; ++r) { float v = acc[jt][r]; sum[r] += v; sq[r] += v * v; }
#pragma unroll
    for (int r = 0; r < 4; ++r)
#pragma unroll
        for (int off = 1; off < 16; off <<= 1) { sum[r] += __shfl_xor(sum[r], off); sq[r] += __shfl_xor(sq[r], off); }
    const int p0 = b * HW + hw0;
#pragma unroll
    for (int r = 0; r < 4; ++r) {
        float mean = sum[r] * (1.f / 256.f);
        float rstd = rsqrtf(sq[r] * (1.f / 256.f) - mean * mean + 1e-5f);
        float* yrow = y + (size_t)(p0 + 4 * lg + r) * 256;
#pragma unroll
        for (int jt = 0; jt < 16; ++jt) {
            int c = jt * 16 + lj;
            yrow[c] = (acc[jt][r] - mean) * rstd * lnw[c] + lnb[c];
        }
    }
}

// ---- n1-LN + q/k/v projections (MFMA), window-ordered bf16 outputs; barrier-free ----
__global__ __launch_bounds__(256) void qkv_k(
    const float* __restrict__ y1f, const float* __restrict__ y2f,
    const float* __restrict__ n1w, const float* __restrict__ n1b,
    const u16* __restrict__ pq, const float* __restrict__ q_b,
    const u16* __restrict__ pkv, const float* __restrict__ kv_b,
    u16* __restrict__ qb, u16* __restrict__ kb, u16* __restrict__ vb) {
    __shared__ __align__(16) u16 A1[64][264];
    __shared__ __align__(16) u16 A2[64][264];
    const int tid = threadIdx.x, w = tid >> 6, l = tid & 63;
    const int lj = l & 15, lg = l >> 4;
    const int blk = blockIdx.x, b = blk / 49;
    const int hwb = (blk % 49) * 64;
    const int p0 = b * HW + hwb;
    const int row0 = w * 16;
    const float4 nw4 = *(const float4*)&n1w[4 * l];
    const float4 nb4 = *(const float4*)&n1b[4 * l];
#pragma unroll
    for (int s = 0; s < 2; ++s) {
        const float* src = s ? y2f : y1f;
        u16(*A)[264] = s ? A2 : A1;
        for (int tk = 0; tk < 16; ++tk) {
            float4 v = *(const float4*)(src + (size_t)(p0 + row0 + tk) * 256 + 4 * l);
            float sm = v.x + v.y + v.z + v.w;
            float sq = v.x * v.x + v.y * v.y + v.z * v.z + v.w * v.w;
#pragma unroll
            for (int off = 1; off < 64; off <<= 1) { sm += __shfl_xor(sm, off); sq += __shfl_xor(sq, off); }
            float mean = sm * (1.f / 256.f);
            float rstd = rsqrtf(sq * (1.f / 256.f) - mean * mean + 1e-5f);
            float a0 = (v.x - mean) * rstd * nw4.x + nb4.x, a1 = (v.y - mean) * rstd * nw4.y + nb4.y;
            float a2 = (v.z - mean) * rstd * nw4.z + nb4.z, a3 = (v.w - mean) * rstd * nw4.w + nb4.w;
            u32* dst = (u32*)&A[row0 + tk][4 * l];
            dst[0] = (u32)f2bf(a0) | ((u32)f2bf(a1) << 16);
            dst[1] = (u32)f2bf(a2) | ((u32)f2bf(a3) << 16);
        }
    }
    int rb[4];
#pragma unroll
    for (int r = 0; r < 4; ++r) {
        int hw = hwb + row0 + 4 * lg + r;
        int hh = hw / 56, ww = hw % 56;
        int win = b * 64 + (hh / 7) * 8 + (ww / 7);
        int nn = (hh % 7) * 7 + (ww % 7);
        rb[r] = (win * 49 + nn) * 256;
    }
    bfrag af[8];
    f32x4 acc[16];
    // Q from A1
#pragma unroll
    for (int kt = 0; kt < 8; ++kt) af[kt] = *(const bfrag*)&A1[row0 + lj][kt * 32 + lg * 8];
#pragma unroll
    for (int jt = 0; jt < 16; ++jt) { float bb = q_b[jt * 16 + lj]; f32x4 t = {bb, bb, bb, bb}; acc[jt] = t; }
#pragma unroll
    for (int jt = 0; jt < 16; ++jt)
#pragma unroll
        for (int kt = 0; kt < 8; ++kt)
            acc[jt] = MFMA16(af[kt], *(const bfrag*)(pq + (size_t)((kt * 16 + jt) * 64 + l) * 8), acc[jt]);
#pragma unroll
    for (int jt = 0; jt < 16; ++jt)
#pragma unroll
        for (int r = 0; r < 4; ++r) qb[rb[r] + jt * 16 + lj] = f2bf(acc[jt][r]);
    // K from A2
#pragma unroll
    for (int kt = 0; kt < 8; ++kt) af[kt] = *(const bfrag*)&A2[row0 + lj][kt * 32 + lg * 8];
#pragma unroll
    for (int jt = 0; jt < 16; ++jt) { float bb = kv_b[jt * 16 + lj]; f32x4 t = {bb, bb, bb, bb}; acc[jt] = t; }
#pragma unroll
    for (int jt = 0; jt < 16; ++jt)
#pragma unroll
        for (int kt = 0; kt < 8; ++kt)
            acc[jt] = MFMA16(af[kt], *(const bfrag*)(pkv + (size_t)((kt * 32 + jt) * 64 + l) * 8), acc[jt]);
#pragma unroll
    for (int jt = 0; jt < 16; ++jt)
#pragma unroll
        for (int r = 0; r < 4; ++r) kb[rb[r] + jt * 16 + lj] = f2bf(acc[jt][r]);
    // V from A2
#pragma unroll
    for (int jt = 0; jt < 16; ++jt) { float bb = kv_b[256 + jt * 16 + lj]; f32x4 t = {bb, bb, bb, bb}; acc[jt] = t; }
#pragma unroll
    for (int jt = 0; jt < 16; ++jt)
#pragma unroll
        for (int kt = 0; kt < 8; ++kt)
            acc[jt] = MFMA16(af[kt], *(const bfrag*)(pkv + (size_t)((kt * 32 + 16 + jt) * 64 + l) * 8), acc[jt]);
#pragma unroll
    for (int jt = 0; jt < 16; ++jt)
#pragma unroll
        for (int r = 0; r < 4; ++r) vb[rb[r] + jt * 16 + lj] = f2bf(acc[jt][r]);
}

// ---- attention per (window, head); scores staged in LDS (no scratch spill) ----
__global__ __launch_bounds__(64) void attn_k(
    const u16* __restrict__ qb, const u16* __restrict__ kb, const u16* __restrict__ vb,
    const float* __restrict__ rel_bias, u16* __restrict__ ob) {
    __shared__ float ks[49][32];
    __shared__ float vs[49][32];
    __shared__ float bs[169];
    __shared__ float ss[49][50];
    const int win = blockIdx.x, head = blockIdx.y;
    const int lane = threadIdx.x;
    const size_t wbase = (size_t)win * 49 * 256 + head * 32;
    for (int t = lane; t < 196; t += 64) {
        int j = t >> 2, c8 = (t & 3) * 8;
        uint4 uk = *(const uint4*)(kb + wbase + (size_t)j * 256 + c8);
        uint4 uv = *(const uint4*)(vb + wbase + (size_t)j * 256 + c8);
        ks[j][c8 + 0] = bflo(uk.x); ks[j][c8 + 1] = bfhi(uk.x);
        ks[j][c8 + 2] = bflo(uk.y); ks[j][c8 + 3] = bfhi(uk.y);
        ks[j][c8 + 4] = bflo(uk.z); ks[j][c8 + 5] = bfhi(uk.z);
        ks[j][c8 + 6] = bflo(uk.w); ks[j][c8 + 7] = bfhi(uk.w);
        vs[j][c8 + 0] = bflo(uv.x); vs[j][c8 + 1] = bfhi(uv.x);
        vs[j][c8 + 2] = bflo(uv.y); vs[j][c8 + 3] = bfhi(uv.y);
        vs[j][c8 + 4] = bflo(uv.z); vs[j][c8 + 5] = bfhi(uv.z);
        vs[j][c8 + 6] = bflo(uv.w); vs[j][c8 + 7] = bfhi(uv.w);
    }
    for (int t = lane; t < 169; t += 64) bs[t] = rel_bias[t * 8 + head];
    __syncthreads();
    if (lane < 49) {
        float qr[32];
        const uint4* qrow = (const uint4*)(qb + wbase + (size_t)lane * 256);
#pragma unroll
        for (int q4 = 0; q4 < 4; ++q4) {
            uint4 u = qrow[q4];
            qr[q4 * 8 + 0] = bflo(u.x); qr[q4 * 8 + 1] = bfhi(u.x);
            qr[q4 * 8 + 2] = bflo(u.y); qr[q4 * 8 + 3] = bfhi(u.y);
            qr[q4 * 8 + 4] = bflo(u.z); qr[q4 * 8 + 5] = bfhi(u.z);
            qr[q4 * 8 + 6] = bflo(u.w); qr[q4 * 8 + 7] = bfhi(u.w);
        }
        const float scale = 0.17677669529663687f;
#pragma unroll
        for (int i = 0; i < 32; ++i) qr[i] *= scale;
        const int yi = lane / 7, xi = lane % 7;
        float mx = -1e30f;
        for (int j = 0; j < 49; ++j) {
            float dot = 0.f;
#pragma unroll
            for (int hd = 0; hd < 32; ++hd) dot += qr[hd] * ks[j][hd];
            dot += bs[(yi - j / 7 + 6) * 13 + (xi - j % 7 + 6)];
            ss[lane][j] = dot;
            mx = fmaxf(mx, dot);
        }
        float denom = 0.f;
        for (int j = 0; j < 49; ++j) { float e = __expf(ss[lane][j] - mx); ss[lane][j] = e; denom += e; }
        const float inv = 1.f / denom;
        const int bwin = win >> 6, wloc = win & 63;
        const int hh = (wloc >> 3) * 7 + yi, ww = (wloc & 7) * 7 + xi;
        u16* orow = ob + ((size_t)bwin * HW + hh * 56 + ww) * 256 + head * 32;
        for (int hd = 0; hd < 32; hd += 2) {
            float a0 = 0.f, a1 = 0.f;
            for (int j = 0; j < 49; ++j) { float p = ss[lane][j]; a0 += p * vs[j][hd]; a1 += p * vs[j][hd + 1]; }
            *(u32*)&orow[hd] = (u32)f2bf(a0 * inv) | ((u32)f2bf(a1 * inv) << 16);
        }
    }
}

// ---- proj + shortcut residual: yo = y1 + o @ proj_w.T + b ----
__global__ __launch_bounds__(256) void proj_k(
    const u16* __restrict__ obuf, const u16* __restrict__ pp,
    const float* __restrict__ proj_b, const float* __restrict__ y1f,
    float* __restrict__ yo) {
    __shared__ __align__(16) u16 A[64][264];
    const int tid = threadIdx.x, w = tid >> 6, l = tid & 63;
    const int lj = l & 15, lg = l >> 4;
    const int blk = blockIdx.x, b = blk / 49;
    const int p0 = b * HW + (blk % 49) * 64;
    const int row0 = w * 16;
#pragma unroll
    for (int t = 0; t < 8; ++t) {
        int rr = row0 + t * 2 + (l >> 5);
        *(uint4*)&A[rr][(l & 31) * 8] = *(const uint4*)(obuf + (size_t)(p0 + rr) * 256 + (l & 31) * 8);
    }
    bfrag af[8];
#pragma unroll
    for (int kt = 0; kt < 8; ++kt) af[kt] = *(const bfrag*)&A[row0 + lj][kt * 32 + lg * 8];
    f32x4 acc[16];
#pragma unroll
    for (int jt = 0; jt < 16; ++jt) { float bb = proj_b[jt * 16 + lj]; f32x4 t = {bb, bb, bb, bb}; acc[jt] = t; }
#pragma unroll
    for (int jt = 0; jt < 16; ++jt)
#pragma unroll
        for (int kt = 0; kt < 8; ++kt)
            acc[jt] = MFMA16(af[kt], *(const bfrag*)(pp + (size_t)((kt * 16 + jt) * 64 + l) * 8), acc[jt]);
#pragma unroll
    for (int jt = 0; jt < 16; ++jt)
#pragma unroll
        for (int r = 0; r < 4; ++r) {
            size_t ad = (size_t)(p0 + row0 + 4 * lg + r) * 256 + jt * 16 + lj;
            yo[ad] = acc[jt][r] + y1f[ad];
        }
}

// ---- token-major -> NCHW transpose of yo (residual source for mlp epilogue) ----
__global__ __launch_bounds__(256) void t2n_k(const float* __restrict__ yo, float* __restrict__ yn) {
    __shared__ float T[4][16][68];
    const int tid = threadIdx.x, w = tid >> 6, l = tid & 63;
    const int lj = l & 15, lg = l >> 4;
    const int blk = blockIdx.x, b = blk / 49;
    const int hwb = (blk % 49) * 64 + w * 16;
    const int c0 = blockIdx.y * 64;
    for (int tk = 0; tk < 16; ++tk)
        T[w][tk][l] = yo[(size_t)(b * HW + hwb + tk) * 256 + c0 + l];
    __syncthreads();
    for (int cc = 0; cc < 16; ++cc) {
        int c = c0 + cc * 4 + lg;
        yn[((size_t)b * 256 + c) * HW + hwb + lj] = T[w][lj][cc * 4 + lg];
    }
}

// ---- n2-LN + fc1 + GELU + fc2 (swapped operands) + residual + NCHW write; barrier-free ----
__global__ __launch_bounds__(256) void mlp_k(
    const float* __restrict__ yo, const float* __restrict__ yn,
    const float* __restrict__ n2w, const float* __restrict__ n2b,
    const u16* __restrict__ pf1, const float* __restrict__ fc1_b,
    const u16* __restrict__ pf2, const float* __restrict__ fc2_b,
    float* __restrict__ out) {
    __shared__ __align__(16) u16 A[64][264];
    __shared__ __align__(16) u16 Hs[64][264];
    const int tid = threadIdx.x, w = tid >> 6, l = tid & 63;
    const int lj = l & 15, lg = l >> 4;
    const int blk = blockIdx.x, b = blk / 49;
    const int hwb = (blk % 49) * 64;
    const int p0 = b * HW + hwb;
    const int row0 = w * 16;
    {   // stage + n2 LayerNorm (wave-private rows)
        const float4 nw4 = *(const float4*)&n2w[4 * l];
        const float4 nb4 = *(const float4*)&n2b[4 * l];
        for (int tk = 0; tk < 16; ++tk) {
            float4 v = *(const float4*)(yo + (size_t)(p0 + row0 + tk) * 256 + 4 * l);
            float sm = v.x + v.y + v.z + v.w;
            float sq = v.x * v.x + v.y * v.y + v.z * v.z + v.w * v.w;
#pragma unroll
            for (int off = 1; off < 64; off <<= 1) { sm += __shfl_xor(sm, off); sq += __shfl_xor(sq, off); }
            float mean = sm * (1.f / 256.f);
            float rstd = rsqrtf(sq * (1.f / 256.f) - mean * mean + 1e-5f);
            float a0 = (v.x - mean) * rstd * nw4.x + nb4.x, a1 = (v.y - mean) * rstd * nw4.y + nb4.y;
            float a2 = (v.z - mean) * rstd * nw4.z + nb4.z, a3 = (v.w - mean) * rstd * nw4.w + nb4.w;
            u32* dst = (u32*)&A[row0 + tk][4 * l];
            dst[0] = (u32)f2bf(a0) | ((u32)f2bf(a1) << 16);
            dst[1] = (u32)f2bf(a2) | ((u32)f2bf(a3) << 16);
        }
    }
    bfrag af[8];
#pragma unroll
    for (int kt = 0; kt < 8; ++kt) af[kt] = *(const bfrag*)&A[row0 + lj][kt * 32 + lg * 8];
    f32x4 acc2[16];
#pragma unroll
    for (int jt = 0; jt < 16; ++jt) acc2[jt] = *(const f32x4*)&fc2_b[jt * 16 + 4 * lg];
    for (int ch = 0; ch < 4; ++ch) {
        // fc1 chunk: 256 h-cols, normal orientation D[token][h]
#pragma unroll
        for (int jt = 0; jt < 16; ++jt) {
            float hb = fc1_b[ch * 256 + jt * 16 + lj];
            f32x4 a1 = {hb, hb, hb, hb};
#pragma unroll
            for (int kt = 0; kt < 8; ++kt)
                a1 = MFMA16(af[kt], *(const bfrag*)(pf1 + (size_t)((kt * 64 + ch * 16 + jt) * 64 + l) * 8), a1);
#pragma unroll
            for (int r = 0; r < 4; ++r) {
                float xv = a1[r];
                float g = 0.5f * xv * (1.f + erff(xv * 0.70710678118654752f));
                float gn = __shfl_down(g, 1);
                if (!(l & 1))
                    *(u32*)&Hs[row0 + 4 * lg + r][jt * 16 + (lj & 14)] = (u32)f2bf(g) | ((u32)f2bf(gn) << 16);
            }
        }
        // fc2 partial: swapped operands -> D[n][token]
#pragma unroll
        for (int hc = 0; hc < 8; ++hc) {
            bfrag hf = *(const bfrag*)&Hs[row0 + lj][hc * 32 + lg * 8];
#pragma unroll
            for (int jt = 0; jt < 16; ++jt)
                acc2[jt] = MFMA16(*(const bfrag*)(pf2 + (size_t)(((ch * 8 + hc) * 16 + jt) * 64 + l) * 8), hf, acc2[jt]);
        }
    }
    const size_t obase = (size_t)b * 256 * HW + hwb + row0 + lj;
#pragma unroll
    for (int jt = 0; jt < 16; ++jt)
#pragma unroll
        for (int r = 0; r < 4; ++r) {
            size_t ad = obase + (size_t)(jt * 16 + 4 * lg + r) * HW;
            out[ad] = yn[ad] + acc2[jt][r];
        }
}

extern "C" void kernel_launch(void* const* d_in, const int* in_sizes, int n_in,
                              void* d_out, int out_size, void* d_ws, size_t ws_size,
                              hipStream_t stream) {
    const float* x1      = (const float*)d_in[0];
    const float* x2      = (const float*)d_in[1];
    const float* pe_w    = (const float*)d_in[2];
    const float* pe_b    = (const float*)d_in[3];
    const float* pe_ln_w = (const float*)d_in[4];
    const float* pe_ln_b = (const float*)d_in[5];
    const float* n1_w    = (const float*)d_in[6];
    const float* n1_b    = (const float*)d_in[7];
    const float* q_w     = (const float*)d_in[8];
    const float* q_b     = (const float*)d_in[9];
    const float* kv_w    = (const float*)d_in[10];
    const float* kv_b    = (const float*)d_in[11];
    const float* rel_bias= (const float*)d_in[12];
    const float* proj_w  = (const float*)d_in[13];
    const float* proj_b  = (const float*)d_in[14];
    const float* n2_w    = (const float*)d_in[15];
    const float* n2_b    = (const float*)d_in[16];
    const float* fc1_w   = (const float*)d_in[17];
    const float* fc1_b   = (const float*)d_in[18];
    const float* fc2_w   = (const float*)d_in[19];
    const float* fc2_b   = (const float*)d_in[20];
    float* out = (float*)d_out;

    float* ws = (float*)d_ws;
    const size_t NTC = (size_t)50176 * 256;
    float* y1 = ws;                 // embed(x1); shortcut
    float* y2 = y1 + NTC;           // embed(x2); reused as yo (post-proj y)
    float* yn = y2 + NTC;           // yo in NCHW layout
    u16* qb   = (u16*)(yn + NTC);
    u16* kb   = qb + NTC;
    u16* vb   = kb + NTC;
    u16* obuf = vb + NTC;
    u16* ppe  = obuf + NTC;
    u16* pq   = ppe + 65536;
    u16* pkv  = pq + 65536;
    u16* pproj= pkv + 131072;
    u16* pf1  = pproj + 65536;
    u16* pf2  = pf1 + 262144;

    pack_k<<<128, 64, 0, stream>>>(pe_w,  ppe,   256, 16);
    pack_k<<<128, 64, 0, stream>>>(q_w,   pq,    256, 16);
    pack_k<<<256, 64, 0, stream>>>(kv_w,  pkv,   256, 32);
    pack_k<<<128, 64, 0, stream>>>(proj_w,pproj, 256, 16);
    pack_k<<<512, 64, 0, stream>>>(fc1_w, pf1,   256, 64);
    pack_k<<<512, 64, 0, stream>>>(fc2_w, pf2,  1024, 16);

    embed_k<<<dim3(784, 2), 256, 0, stream>>>(x1, x2, ppe, pe_b, pe_ln_w, pe_ln_b, y1, y2);
    qkv_k<<<784, 256, 0, stream>>>(y1, y2, n1_w, n1_b, pq, q_b, pkv, kv_b, qb, kb, vb);
    attn_k<<<dim3(1024, 8), 64, 0, stream>>>(qb, kb, vb, rel_bias, obuf);
    proj_k<<<784, 256, 0, stream>>>(obuf, pproj, proj_b, y1, y2);
    t2n_k<<<dim3(784, 4), 256, 0, stream>>>(y2, yn);
    mlp_k<<<784, 256, 0, stream>>>(y2, yn, n2_w, n2_b, pf1, fc1_b, pf2, fc2_b, out);
}

// Round 4
// 801.418 us; speedup vs baseline: 3.0198x; 1.5387x over previous
//
#include <hip/hip_runtime.h>
#include <math.h>

#define HW 3136
typedef unsigned short u16;
typedef unsigned int u32;
typedef __attribute__((ext_vector_type(8))) short bfrag;   // 8 bf16 (4 VGPRs)
typedef __attribute__((ext_vector_type(4))) float f32x4;   // MFMA accumulator

#define MFMA16(A, B, C) __builtin_amdgcn_mfma_f32_16x16x32_bf16(A, B, C, 0, 0, 0)

__device__ __forceinline__ u16 f2bf(float f) {            // RNE float->bf16
    u32 u = __builtin_bit_cast(u32, f);
    u = (u + 0x7fffu + ((u >> 16) & 1u)) >> 16;
    return (u16)u;
}
__device__ __forceinline__ float bflo(u32 v) { return __builtin_bit_cast(float, v << 16); }
__device__ __forceinline__ float bfhi(u32 v) { return __builtin_bit_cast(float, v & 0xffff0000u); }

typedef __attribute__((address_space(1))) const unsigned int g_u32;
typedef __attribute__((address_space(3))) unsigned int l_u32;
__device__ __forceinline__ void gl_lds16(const u16* g, u16* l) {
    // async global->LDS, 16B per lane; LDS dest = wave-uniform base + lane*16
    __builtin_amdgcn_global_load_lds((g_u32*)g, (l_u32*)l, 16, 0, 0);
}

// ---- pack W [N][K] fp32 into MFMA fragment order, kt-major tiles (tile = kt*NT + jt) ----
__global__ void pack_k(const float* __restrict__ W, u16* __restrict__ out, int K, int NT) {
    const int tile = blockIdx.x, l = threadIdx.x;
    const int kt = tile / NT, jt = tile % NT;
    const int n = jt * 16 + (l & 15);
    const int k0 = kt * 32 + (l >> 4) * 8;
    const float* src = W + (size_t)n * K + k0;
    float4 s0 = *(const float4*)src;
    float4 s1 = *(const float4*)(src + 4);
    uint4 u;
    u.x = (u32)f2bf(s0.x) | ((u32)f2bf(s0.y) << 16);
    u.y = (u32)f2bf(s0.z) | ((u32)f2bf(s0.w) << 16);
    u.z = (u32)f2bf(s1.x) | ((u32)f2bf(s1.y) << 16);
    u.w = (u32)f2bf(s1.z) | ((u32)f2bf(s1.w) << 16);
    *(uint4*)(out + ((size_t)tile * 64 + l) * 8) = u;
}

// ---- pack, jt-major tiles (tile = jt*KT + kt) -> per-jt chunks contiguous for LDS staging ----
__global__ void pack_jt_k(const float* __restrict__ W, u16* __restrict__ out, int K, int KT) {
    const int tile = blockIdx.x, l = threadIdx.x;
    const int jt = tile / KT, kt = tile % KT;
    const int n = jt * 16 + (l & 15);
    const int k0 = kt * 32 + (l >> 4) * 8;
    const float* src = W + (size_t)n * K + k0;
    float4 s0 = *(const float4*)src;
    float4 s1 = *(const float4*)(src + 4);
    uint4 u;
    u.x = (u32)f2bf(s0.x) | ((u32)f2bf(s0.y) << 16);
    u.y = (u32)f2bf(s0.z) | ((u32)f2bf(s0.w) << 16);
    u.z = (u32)f2bf(s1.x) | ((u32)f2bf(s1.y) << 16);
    u.w = (u32)f2bf(s1.z) | ((u32)f2bf(s1.w) << 16);
    *(uint4*)(out + ((size_t)tile * 64 + l) * 8) = u;
}

// ---- embed: y = LN(pe_w @ x + pe_b); A-fragments gathered straight from NCHW x ----
__global__ __launch_bounds__(256) void embed_k(
    const float* __restrict__ x1, const float* __restrict__ x2,
    const u16* __restrict__ wp, const float* __restrict__ pe_b,
    const float* __restrict__ lnw, const float* __restrict__ lnb,
    float* __restrict__ y1, float* __restrict__ y2) {
    const float* x = blockIdx.y ? x2 : x1;
    float* y = blockIdx.y ? y2 : y1;
    const int tid = threadIdx.x, w = tid >> 6, l = tid & 63;
    const int lj = l & 15, lg = l >> 4;
    const int blk = blockIdx.x, b = blk / 49;
    const int hw0 = (blk % 49) * 64 + w * 16;     // wave's 16 tokens
    const float* xb = x + (size_t)b * 256 * HW + hw0 + lj;
    bfrag af[8];
#pragma unroll
    for (int kt = 0; kt < 8; ++kt)
#pragma unroll
        for (int bb = 0; bb < 8; ++bb)
            af[kt][bb] = (short)f2bf(xb[(size_t)(kt * 32 + lg * 8 + bb) * HW]);
    f32x4 acc[16];
#pragma unroll
    for (int jt = 0; jt < 16; ++jt) { float bb = pe_b[jt * 16 + lj]; f32x4 t = {bb, bb, bb, bb}; acc[jt] = t; }
#pragma unroll
    for (int jt = 0; jt < 16; ++jt)
#pragma unroll
        for (int kt = 0; kt < 8; ++kt)
            acc[jt] = MFMA16(af[kt], *(const bfrag*)(wp + (size_t)((kt * 16 + jt) * 64 + l) * 8), acc[jt]);
    // LayerNorm: token row = 4*lg + r lives in this lane's 16-lane group
    float sum[4] = {0, 0, 0, 0}, sq[4] = {0, 0, 0, 0};
#pragma unroll
    for (int jt = 0; jt < 16; ++jt)
#pragma unroll
        for (int r = 0; r < 4; ++r) { float v = acc[jt][r]; sum[r] += v; sq[r] += v * v; }
#pragma unroll
    for (int r = 0; r < 4; ++r)
#pragma unroll
        for (int off = 1; off < 16; off <<= 1) { sum[r] += __shfl_xor(sum[r], off); sq[r] += __shfl_xor(sq[r], off); }
    const int p0 = b * HW + hw0;
#pragma unroll
    for (int r = 0; r < 4; ++r) {
        float mean = sum[r] * (1.f / 256.f);
        float rstd = rsqrtf(sq[r] * (1.f / 256.f) - mean * mean + 1e-5f);
        float* yrow = y + (size_t)(p0 + 4 * lg + r) * 256;
#pragma unroll
        for (int jt = 0; jt < 16; ++jt) {
            int c = jt * 16 + lj;
            yrow[c] = (acc[jt][r] - mean) * rstd * lnw[c] + lnb[c];
        }
    }
}

// ---- n1-LN + q/k/v projections; weights LDS-staged (dbuf) & shared across waves ----
__global__ __launch_bounds__(256) void qkv_k(
    const float* __restrict__ y1f, const float* __restrict__ y2f,
    const float* __restrict__ n1w, const float* __restrict__ n1b,
    const u16* __restrict__ pq, const float* __restrict__ q_b,
    const u16* __restrict__ pkv, const float* __restrict__ kv_b,
    u16* __restrict__ qb, u16* __restrict__ kb, u16* __restrict__ vb) {
    __shared__ __align__(16) u16 sh[16896];   // A-tile [64][264] ∪ weight dbuf 2×8192
    const int tid = threadIdx.x, wv = tid >> 6, l = tid & 63;
    const int lj = l & 15, lg = l >> 4;
    const int blk = blockIdx.x, b = blk / 49;
    const int hwb = (blk % 49) * 64;
    const int p0 = b * HW + hwb;
    const int row0 = wv * 16;
    u16(*A)[264] = (u16(*)[264])sh;
    const float4 nw4 = *(const float4*)&n1w[4 * l];
    const float4 nb4 = *(const float4*)&n1b[4 * l];
    bfrag af1[8], af2[8];
#pragma unroll
    for (int s = 0; s < 2; ++s) {
        const float* src = s ? y2f : y1f;
        for (int tk = 0; tk < 16; ++tk) {   // LN one token per iteration (wave-private rows)
            float4 v = *(const float4*)(src + (size_t)(p0 + row0 + tk) * 256 + 4 * l);
            float sm = v.x + v.y + v.z + v.w;
            float sq = v.x * v.x + v.y * v.y + v.z * v.z + v.w * v.w;
#pragma unroll
            for (int off = 1; off < 64; off <<= 1) { sm += __shfl_xor(sm, off); sq += __shfl_xor(sq, off); }
            float mean = sm * (1.f / 256.f);
            float rstd = rsqrtf(sq * (1.f / 256.f) - mean * mean + 1e-5f);
            float a0 = (v.x - mean) * rstd * nw4.x + nb4.x, a1 = (v.y - mean) * rstd * nw4.y + nb4.y;
            float a2 = (v.z - mean) * rstd * nw4.z + nb4.z, a3 = (v.w - mean) * rstd * nw4.w + nb4.w;
            u32* dst = (u32*)&A[row0 + tk][4 * l];
            dst[0] = (u32)f2bf(a0) | ((u32)f2bf(a1) << 16);
            dst[1] = (u32)f2bf(a2) | ((u32)f2bf(a3) << 16);
        }
        if (s == 0) {
#pragma unroll
            for (int kt = 0; kt < 8; ++kt) af1[kt] = *(const bfrag*)&A[row0 + lj][kt * 32 + lg * 8];
        } else {
#pragma unroll
            for (int kt = 0; kt < 8; ++kt) af2[kt] = *(const bfrag*)&A[row0 + lj][kt * 32 + lg * 8];
        }
    }
    int rb[4];
#pragma unroll
    for (int r = 0; r < 4; ++r) {
        int hw = hwb + row0 + 4 * lg + r;
        int hh = hw / 56, ww = hw % 56;
        int win = b * 64 + (hh / 7) * 8 + (ww / 7);
        int nn = (hh % 7) * 7 + (ww % 7);
        rb[r] = (win * 49 + nn) * 256;
    }
    __syncthreads();           // all waves done reading A before weight staging reuses it

    auto stage = [&](int c, int bufsel) {
        const u16* src = (c < 8) ? pq + (size_t)c * 8192
                       : (c < 16) ? pkv + (size_t)(c - 8) * 8192
                                  : pkv + 65536 + (size_t)(c - 16) * 8192;
        u16* dbase = sh + bufsel * 8192 + wv * 512;
        const u16* gsrc = src + wv * 512 + l * 8;
#pragma unroll
        for (int r = 0; r < 4; ++r)
            gl_lds16(gsrc + r * 2048, dbase + r * 2048);
    };
    auto do_chunk = [&](int cl, const bfrag (&af)[8], const float* bias, u16* dst, const u16* WBb) {
#pragma unroll
        for (int jtl = 0; jtl < 2; ++jtl) {
            const int jt = cl * 2 + jtl;
            float bb = bias[jt * 16 + lj];
            f32x4 acc = {bb, bb, bb, bb};
#pragma unroll
            for (int kt = 0; kt < 8; ++kt)
                acc = MFMA16(af[kt], *(const bfrag*)&WBb[(jtl * 8 + kt) * 512 + l * 8], acc);
#pragma unroll
            for (int r = 0; r < 4; ++r) dst[rb[r] + jt * 16 + lj] = f2bf(acc[r]);
        }
    };

    stage(0, 0);
    __syncthreads();
    int buf = 0;
    for (int c = 0; c < 24; ++c) {
        if (c < 23) stage(c + 1, buf ^ 1);
        const u16* WBb = sh + buf * 8192;
        if (c < 8)       do_chunk(c,      af1, q_b,        qb, WBb);
        else if (c < 16) do_chunk(c - 8,  af2, kv_b,       kb, WBb);
        else             do_chunk(c - 16, af2, kv_b + 256, vb, WBb);
        __syncthreads();
        buf ^= 1;
    }
}

// ---- attention per (window, head); scores staged in LDS (no scratch spill) ----
__global__ __launch_bounds__(64) void attn_k(
    const u16* __restrict__ qb, const u16* __restrict__ kb, const u16* __restrict__ vb,
    const float* __restrict__ rel_bias, u16* __restrict__ ob) {
    __shared__ float ks[49][32];
    __shared__ float vs[49][32];
    __shared__ float bs[169];
    __shared__ float ss[49][50];
    const int win = blockIdx.x, head = blockIdx.y;
    const int lane = threadIdx.x;
    const size_t wbase = (size_t)win * 49 * 256 + head * 32;
    for (int t = lane; t < 196; t += 64) {
        int j = t >> 2, c8 = (t & 3) * 8;
        uint4 uk = *(const uint4*)(kb + wbase + (size_t)j * 256 + c8);
        uint4 uv = *(const uint4*)(vb + wbase + (size_t)j * 256 + c8);
        ks[j][c8 + 0] = bflo(uk.x); ks[j][c8 + 1] = bfhi(uk.x);
        ks[j][c8 + 2] = bflo(uk.y); ks[j][c8 + 3] = bfhi(uk.y);
        ks[j][c8 + 4] = bflo(uk.z); ks[j][c8 + 5] = bfhi(uk.z);
        ks[j][c8 + 6] = bflo(uk.w); ks[j][c8 + 7] = bfhi(uk.w);
        vs[j][c8 + 0] = bflo(uv.x); vs[j][c8 + 1] = bfhi(uv.x);
        vs[j][c8 + 2] = bflo(uv.y); vs[j][c8 + 3] = bfhi(uv.y);
        vs[j][c8 + 4] = bflo(uv.z); vs[j][c8 + 5] = bfhi(uv.z);
        vs[j][c8 + 6] = bflo(uv.w); vs[j][c8 + 7] = bfhi(uv.w);
    }
    for (int t = lane; t < 169; t += 64) bs[t] = rel_bias[t * 8 + head];
    __syncthreads();
    if (lane < 49) {
        float qr[32];
        const uint4* qrow = (const uint4*)(qb + wbase + (size_t)lane * 256);
#pragma unroll
        for (int q4 = 0; q4 < 4; ++q4) {
            uint4 u = qrow[q4];
            qr[q4 * 8 + 0] = bflo(u.x); qr[q4 * 8 + 1] = bfhi(u.x);
            qr[q4 * 8 + 2] = bflo(u.y); qr[q4 * 8 + 3] = bfhi(u.y);
            qr[q4 * 8 + 4] = bflo(u.z); qr[q4 * 8 + 5] = bfhi(u.z);
            qr[q4 * 8 + 6] = bflo(u.w); qr[q4 * 8 + 7] = bfhi(u.w);
        }
        const float scale = 0.17677669529663687f;
#pragma unroll
        for (int i = 0; i < 32; ++i) qr[i] *= scale;
        const int yi = lane / 7, xi = lane % 7;
        float mx = -1e30f;
        for (int j = 0; j < 49; ++j) {
            float dot = 0.f;
#pragma unroll
            for (int hd = 0; hd < 32; ++hd) dot += qr[hd] * ks[j][hd];
            dot += bs[(yi - j / 7 + 6) * 13 + (xi - j % 7 + 6)];
            ss[lane][j] = dot;
            mx = fmaxf(mx, dot);
        }
        float denom = 0.f;
        for (int j = 0; j < 49; ++j) { float e = __expf(ss[lane][j] - mx); ss[lane][j] = e; denom += e; }
        const float inv = 1.f / denom;
        const int bwin = win >> 6, wloc = win & 63;
        const int hh = (wloc >> 3) * 7 + yi, ww = (wloc & 7) * 7 + xi;
        u16* orow = ob + ((size_t)bwin * HW + hh * 56 + ww) * 256 + head * 32;
        for (int hd = 0; hd < 32; hd += 2) {
            float a0 = 0.f, a1 = 0.f;
            for (int j = 0; j < 49; ++j) { float p = ss[lane][j]; a0 += p * vs[j][hd]; a1 += p * vs[j][hd + 1]; }
            *(u32*)&orow[hd] = (u32)f2bf(a0 * inv) | ((u32)f2bf(a1 * inv) << 16);
        }
    }
}

// ---- proj + shortcut residual: yo = y1 + o @ proj_w.T + b ----
__global__ __launch_bounds__(256) void proj_k(
    const u16* __restrict__ obuf, const u16* __restrict__ pp,
    const float* __restrict__ proj_b, const float* __restrict__ y1f,
    float* __restrict__ yo) {
    __shared__ __align__(16) u16 A[64][264];
    const int tid = threadIdx.x, w = tid >> 6, l = tid & 63;
    const int lj = l & 15, lg = l >> 4;
    const int blk = blockIdx.x, b = blk / 49;
    const int p0 = b * HW + (blk % 49) * 64;
    const int row0 = w * 16;
#pragma unroll
    for (int t = 0; t < 8; ++t) {
        int rr = row0 + t * 2 + (l >> 5);
        *(uint4*)&A[rr][(l & 31) * 8] = *(const uint4*)(obuf + (size_t)(p0 + rr) * 256 + (l & 31) * 8);
    }
    bfrag af[8];
#pragma unroll
    for (int kt = 0; kt < 8; ++kt) af[kt] = *(const bfrag*)&A[row0 + lj][kt * 32 + lg * 8];
    f32x4 acc[16];
#pragma unroll
    for (int jt = 0; jt < 16; ++jt) { float bb = proj_b[jt * 16 + lj]; f32x4 t = {bb, bb, bb, bb}; acc[jt] = t; }
#pragma unroll
    for (int jt = 0; jt < 16; ++jt)
#pragma unroll
        for (int kt = 0; kt < 8; ++kt)
            acc[jt] = MFMA16(af[kt], *(const bfrag*)(pp + (size_t)((kt * 16 + jt) * 64 + l) * 8), acc[jt]);
#pragma unroll
    for (int jt = 0; jt < 16; ++jt)
#pragma unroll
        for (int r = 0; r < 4; ++r) {
            size_t ad = (size_t)(p0 + row0 + 4 * lg + r) * 256 + jt * 16 + lj;
            yo[ad] = acc[jt][r] + y1f[ad];
        }
}

// ---- token-major -> NCHW transpose of yo (residual source for mlp epilogue) ----
__global__ __launch_bounds__(256) void t2n_k(const float* __restrict__ yo, float* __restrict__ yn) {
    __shared__ float T[4][16][68];
    const int tid = threadIdx.x, w = tid >> 6, l = tid & 63;
    const int lj = l & 15, lg = l >> 4;
    const int blk = blockIdx.x, b = blk / 49;
    const int hwb = (blk % 49) * 64 + w * 16;
    const int c0 = blockIdx.y * 64;
    for (int tk = 0; tk < 16; ++tk)
        T[w][tk][l] = yo[(size_t)(b * HW + hwb + tk) * 256 + c0 + l];
    __syncthreads();
    for (int cc = 0; cc < 16; ++cc) {
        int c = c0 + cc * 4 + lg;
        yn[((size_t)b * 256 + c) * HW + hwb + lj] = T[w][lj][cc * 4 + lg];
    }
}

// ---- n2-LN + fc1 + GELU + fc2; weights LDS-staged (dbuf) per 32-h chunk ----
__global__ __launch_bounds__(256) void mlp_k(
    const float* __restrict__ yo, const float* __restrict__ yn,
    const float* __restrict__ n2w, const float* __restrict__ n2b,
    const u16* __restrict__ pf1, const float* __restrict__ fc1_b,
    const u16* __restrict__ pf2, const float* __restrict__ fc2_b,
    float* __restrict__ out) {
    __shared__ __align__(16) u16 sh[32768];   // A-tile [64][264] ∪ weight dbuf 2×16384
    __shared__ __align__(16) u16 Hs[64][40];  // GELU'd h chunk (transpose buffer)
    const int tid = threadIdx.x, wv = tid >> 6, l = tid & 63;
    const int lj = l & 15, lg = l >> 4;
    const int blk = blockIdx.x, b = blk / 49;
    const int hwb = (blk % 49) * 64;
    const int p0 = b * HW + hwb;
    const int row0 = wv * 16;
    u16(*A)[264] = (u16(*)[264])sh;
    {   // stage + n2 LayerNorm (wave-private rows)
        const float4 nw4 = *(const float4*)&n2w[4 * l];
        const float4 nb4 = *(const float4*)&n2b[4 * l];
        for (int tk = 0; tk < 16; ++tk) {
            float4 v = *(const float4*)(yo + (size_t)(p0 + row0 + tk) * 256 + 4 * l);
            float sm = v.x + v.y + v.z + v.w;
            float sq = v.x * v.x + v.y * v.y + v.z * v.z + v.w * v.w;
#pragma unroll
            for (int off = 1; off < 64; off <<= 1) { sm += __shfl_xor(sm, off); sq += __shfl_xor(sq, off); }
            float mean = sm * (1.f / 256.f);
            float rstd = rsqrtf(sq * (1.f / 256.f) - mean * mean + 1e-5f);
            float a0 = (v.x - mean) * rstd * nw4.x + nb4.x, a1 = (v.y - mean) * rstd * nw4.y + nb4.y;
            float a2 = (v.z - mean) * rstd * nw4.z + nb4.z, a3 = (v.w - mean) * rstd * nw4.w + nb4.w;
            u32* dst = (u32*)&A[row0 + tk][4 * l];
            dst[0] = (u32)f2bf(a0) | ((u32)f2bf(a1) << 16);
            dst[1] = (u32)f2bf(a2) | ((u32)f2bf(a3) << 16);
        }
    }
    bfrag af[8];
#pragma unroll
    for (int kt = 0; kt < 8; ++kt) af[kt] = *(const bfrag*)&A[row0 + lj][kt * 32 + lg * 8];
    f32x4 acc2[16];
#pragma unroll
    for (int jt = 0; jt < 16; ++jt) acc2[jt] = *(const f32x4*)&fc2_b[jt * 16 + 4 * lg];
    __syncthreads();           // all waves done reading A before weight staging reuses it

    auto stage = [&](int c, int bufsel) {
        const u16* s1 = pf1 + (size_t)c * 8192;
        const u16* s2 = pf2 + (size_t)c * 8192;
        u16* dbase = sh + bufsel * 16384 + wv * 512;
        const int goff = wv * 512 + l * 8;
#pragma unroll
        for (int r = 0; r < 4; ++r) {
            gl_lds16(s1 + r * 2048 + goff, dbase + r * 2048);
            gl_lds16(s2 + r * 2048 + goff, dbase + 8192 + r * 2048);
        }
    };

    stage(0, 0);
    __syncthreads();
    int buf = 0;
    for (int c = 0; c < 32; ++c) {
        if (c < 31) stage(c + 1, buf ^ 1);
        const u16* WBb = sh + buf * 16384;
        // fc1: 2 jt-tiles (32 h-cols) + GELU -> Hs
#pragma unroll
        for (int jtl = 0; jtl < 2; ++jtl) {
            float hb = fc1_b[c * 32 + jtl * 16 + lj];
            f32x4 a1 = {hb, hb, hb, hb};
#pragma unroll
            for (int kt = 0; kt < 8; ++kt)
                a1 = MFMA16(af[kt], *(const bfrag*)&WBb[(jtl * 8 + kt) * 512 + l * 8], a1);
#pragma unroll
            for (int r = 0; r < 4; ++r) {
                float xv = a1[r];
                float g = 0.5f * xv * (1.f + erff(xv * 0.70710678118654752f));
                float gn = __shfl_down(g, 1);
                if (!(l & 1))
                    *(u32*)&Hs[row0 + 4 * lg + r][jtl * 16 + (lj & 14)] = (u32)f2bf(g) | ((u32)f2bf(gn) << 16);
            }
        }
        // fc2 partial for this 32-h k-slice (swapped operands -> D[n][token])
        bfrag hf = *(const bfrag*)&Hs[row0 + lj][lg * 8];
#pragma unroll
        for (int jt = 0; jt < 16; ++jt)
            acc2[jt] = MFMA16(*(const bfrag*)&WBb[8192 + jt * 512 + l * 8], hf, acc2[jt]);
        __syncthreads();
        buf ^= 1;
    }
    const size_t obase = (size_t)b * 256 * HW + hwb + row0 + lj;
#pragma unroll
    for (int jt = 0; jt < 16; ++jt)
#pragma unroll
        for (int r = 0; r < 4; ++r) {
            size_t ad = obase + (size_t)(jt * 16 + 4 * lg + r) * HW;
            out[ad] = yn[ad] + acc2[jt][r];
        }
}

extern "C" void kernel_launch(void* const* d_in, const int* in_sizes, int n_in,
                              void* d_out, int out_size, void* d_ws, size_t ws_size,
                              hipStream_t stream) {
    const float* x1      = (const float*)d_in[0];
    const float* x2      = (const float*)d_in[1];
    const float* pe_w    = (const float*)d_in[2];
    const float* pe_b    = (const float*)d_in[3];
    const float* pe_ln_w = (const float*)d_in[4];
    const float* pe_ln_b = (const float*)d_in[5];
    const float* n1_w    = (const float*)d_in[6];
    const float* n1_b    = (const float*)d_in[7];
    const float* q_w     = (const float*)d_in[8];
    const float* q_b     = (const float*)d_in[9];
    const float* kv_w    = (const float*)d_in[10];
    const float* kv_b    = (const float*)d_in[11];
    const float* rel_bias= (const float*)d_in[12];
    const float* proj_w  = (const float*)d_in[13];
    const float* proj_b  = (const float*)d_in[14];
    const float* n2_w    = (const float*)d_in[15];
    const float* n2_b    = (const float*)d_in[16];
    const float* fc1_w   = (const float*)d_in[17];
    const float* fc1_b   = (const float*)d_in[18];
    const float* fc2_w   = (const float*)d_in[19];
    const float* fc2_b   = (const float*)d_in[20];
    float* out = (float*)d_out;

    float* ws = (float*)d_ws;
    const size_t NTC = (size_t)50176 * 256;
    float* y1 = ws;                 // embed(x1); shortcut
    float* y2 = y1 + NTC;           // embed(x2); reused as yo (post-proj y)
    float* yn = y2 + NTC;           // yo in NCHW layout
    u16* qb   = (u16*)(yn + NTC);
    u16* kb   = qb + NTC;
    u16* vb   = kb + NTC;
    u16* obuf = vb + NTC;
    u16* ppe  = obuf + NTC;
    u16* pq   = ppe + 65536;
    u16* pkv  = pq + 65536;
    u16* pproj= pkv + 131072;
    u16* pf1  = pproj + 65536;
    u16* pf2  = pf1 + 262144;

    pack_k  <<<128, 64, 0, stream>>>(pe_w,  ppe,   256, 16);   // kt-major (embed)
    pack_jt_k<<<128, 64, 0, stream>>>(q_w,   pq,    256, 8);   // jt-major (staged)
    pack_jt_k<<<256, 64, 0, stream>>>(kv_w,  pkv,   256, 8);   // jt-major (staged)
    pack_k  <<<128, 64, 0, stream>>>(proj_w,pproj, 256, 16);   // kt-major (proj)
    pack_jt_k<<<512, 64, 0, stream>>>(fc1_w, pf1,   256, 8);   // jt-major (staged)
    pack_k  <<<512, 64, 0, stream>>>(fc2_w, pf2,  1024, 16);   // kt-major == per-k-tile chunks

    embed_k<<<dim3(784, 2), 256, 0, stream>>>(x1, x2, ppe, pe_b, pe_ln_w, pe_ln_b, y1, y2);
    qkv_k<<<784, 256, 0, stream>>>(y1, y2, n1_w, n1_b, pq, q_b, pkv, kv_b, qb, kb, vb);
    attn_k<<<dim3(1024, 8), 64, 0, stream>>>(qb, kb, vb, rel_bias, obuf);
    proj_k<<<784, 256, 0, stream>>>(obuf, pproj, proj_b, y1, y2);
    t2n_k<<<dim3(784, 4), 256, 0, stream>>>(y2, yn);
    mlp_k<<<784, 256, 0, stream>>>(y2, yn, n2_w, n2_b, pf1, fc1_b, pf2, fc2_b, out);
}

// Round 5
// 688.449 us; speedup vs baseline: 3.5153x; 1.1641x over previous
//
#include <hip/hip_runtime.h>
#include <math.h>

#define HW 3136
typedef unsigned short u16;
typedef unsigned int u32;
typedef __attribute__((ext_vector_type(8))) short bfrag;   // 8 bf16 (4 VGPRs)
typedef __attribute__((ext_vector_type(4))) float f32x4;   // MFMA accumulator

#define MFMA16(A, B, C) __builtin_amdgcn_mfma_f32_16x16x32_bf16(A, B, C, 0, 0, 0)

__device__ __forceinline__ u16 f2bf(float f) {            // RNE float->bf16
    u32 u = __builtin_bit_cast(u32, f);
    u = (u + 0x7fffu + ((u >> 16) & 1u)) >> 16;
    return (u16)u;
}
__device__ __forceinline__ float bflo(u32 v) { return __builtin_bit_cast(float, v << 16); }
__device__ __forceinline__ float bfhi(u32 v) { return __builtin_bit_cast(float, v & 0xffff0000u); }

typedef __attribute__((address_space(1))) const unsigned int g_u32;
typedef __attribute__((address_space(3))) unsigned int l_u32;
__device__ __forceinline__ void gl_lds16(const u16* g, u16* l) {
    // async global->LDS, 16B per lane; LDS dest = wave-uniform base + lane*16
    __builtin_amdgcn_global_load_lds((g_u32*)g, (l_u32*)l, 16, 0, 0);
}

// ---- pack W [N][K] fp32 into MFMA fragment order, kt-major tiles (tile = kt*NT + jt) ----
__global__ void pack_k(const float* __restrict__ W, u16* __restrict__ out, int K, int NT) {
    const int tile = blockIdx.x, l = threadIdx.x;
    const int kt = tile / NT, jt = tile % NT;
    const int n = jt * 16 + (l & 15);
    const int k0 = kt * 32 + (l >> 4) * 8;
    const float* src = W + (size_t)n * K + k0;
    float4 s0 = *(const float4*)src;
    float4 s1 = *(const float4*)(src + 4);
    uint4 u;
    u.x = (u32)f2bf(s0.x) | ((u32)f2bf(s0.y) << 16);
    u.y = (u32)f2bf(s0.z) | ((u32)f2bf(s0.w) << 16);
    u.z = (u32)f2bf(s1.x) | ((u32)f2bf(s1.y) << 16);
    u.w = (u32)f2bf(s1.z) | ((u32)f2bf(s1.w) << 16);
    *(uint4*)(out + ((size_t)tile * 64 + l) * 8) = u;
}

// ---- pack, jt-major tiles (tile = jt*KT + kt) -> per-jt chunks contiguous for LDS staging ----
__global__ void pack_jt_k(const float* __restrict__ W, u16* __restrict__ out, int K, int KT) {
    const int tile = blockIdx.x, l = threadIdx.x;
    const int jt = tile / KT, kt = tile % KT;
    const int n = jt * 16 + (l & 15);
    const int k0 = kt * 32 + (l >> 4) * 8;
    const float* src = W + (size_t)n * K + k0;
    float4 s0 = *(const float4*)src;
    float4 s1 = *(const float4*)(src + 4);
    uint4 u;
    u.x = (u32)f2bf(s0.x) | ((u32)f2bf(s0.y) << 16);
    u.y = (u32)f2bf(s0.z) | ((u32)f2bf(s0.w) << 16);
    u.z = (u32)f2bf(s1.x) | ((u32)f2bf(s1.y) << 16);
    u.w = (u32)f2bf(s1.z) | ((u32)f2bf(s1.w) << 16);
    *(uint4*)(out + ((size_t)tile * 64 + l) * 8) = u;
}

// ---- embed: y = LN(pe_w @ x + pe_b); weights LDS-staged (dbuf), A-frags from NCHW x ----
__global__ __launch_bounds__(256) void embed_k(
    const float* __restrict__ x1, const float* __restrict__ x2,
    const u16* __restrict__ wp, const float* __restrict__ pe_b,
    const float* __restrict__ lnw, const float* __restrict__ lnb,
    float* __restrict__ y1, float* __restrict__ y2) {
    __shared__ __align__(16) u16 sh[2][8192];   // weight dbuf, 2 x 16KB (2 jt-tiles each)
    const float* x = blockIdx.y ? x2 : x1;
    float* y = blockIdx.y ? y2 : y1;
    const int tid = threadIdx.x, wv = tid >> 6, l = tid & 63;
    const int lj = l & 15, lg = l >> 4;
    const int blk = blockIdx.x, b = blk / 49;
    const int hw0 = (blk % 49) * 64 + wv * 16;     // wave's 16 tokens
    const float* xb = x + (size_t)b * 256 * HW + hw0 + lj;
    bfrag af[8];
#pragma unroll
    for (int kt = 0; kt < 8; ++kt)
#pragma unroll
        for (int bb = 0; bb < 8; ++bb)
            af[kt][bb] = (short)f2bf(xb[(size_t)(kt * 32 + lg * 8 + bb) * HW]);
    f32x4 acc[16];
#pragma unroll
    for (int jt = 0; jt < 16; ++jt) { float bb = pe_b[jt * 16 + lj]; f32x4 t = {bb, bb, bb, bb}; acc[jt] = t; }

    auto stage = [&](int c, int bufsel) {
        const u16* gsrc = wp + (size_t)c * 8192 + wv * 512 + l * 8;
        u16* dbase = &sh[bufsel][wv * 512];
#pragma unroll
        for (int r = 0; r < 4; ++r)
            gl_lds16(gsrc + r * 2048, dbase + r * 2048);
    };
    stage(0, 0);
    __syncthreads();
    int buf = 0;
#pragma unroll
    for (int c = 0; c < 8; ++c) {
        if (c < 7) stage(c + 1, buf ^ 1);
        const u16* WBb = sh[buf];
#pragma unroll
        for (int jtl = 0; jtl < 2; ++jtl) {
            const int jt = c * 2 + jtl;
#pragma unroll
            for (int kt = 0; kt < 8; ++kt)
                acc[jt] = MFMA16(af[kt], *(const bfrag*)&WBb[(jtl * 8 + kt) * 512 + l * 8], acc[jt]);
        }
        __syncthreads();
        buf ^= 1;
    }
    // LayerNorm: token row = 4*lg + r lives in this lane's 16-lane group
    float sum[4] = {0, 0, 0, 0}, sq[4] = {0, 0, 0, 0};
#pragma unroll
    for (int jt = 0; jt < 16; ++jt)
#pragma unroll
        for (int r = 0; r < 4; ++r) { float v = acc[jt][r]; sum[r] += v; sq[r] += v * v; }
#pragma unroll
    for (int r = 0; r < 4; ++r)
#pragma unroll
        for (int off = 1; off < 16; off <<= 1) { sum[r] += __shfl_xor(sum[r], off); sq[r] += __shfl_xor(sq[r], off); }
    const int p0 = b * HW + hw0;
#pragma unroll
    for (int r = 0; r < 4; ++r) {
        float mean = sum[r] * (1.f / 256.f);
        float rstd = rsqrtf(sq[r] * (1.f / 256.f) - mean * mean + 1e-5f);
        float* yrow = y + (size_t)(p0 + 4 * lg + r) * 256;
#pragma unroll
        for (int jt = 0; jt < 16; ++jt) {
            int c = jt * 16 + lj;
            yrow[c] = (acc[jt][r] - mean) * rstd * lnw[c] + lnb[c];
        }
    }
}

// ---- n1-LN + q/k/v projections; weights LDS-staged (dbuf) & shared across waves ----
__global__ __launch_bounds__(256) void qkv_k(
    const float* __restrict__ y1f, const float* __restrict__ y2f,
    const float* __restrict__ n1w, const float* __restrict__ n1b,
    const u16* __restrict__ pq, const float* __restrict__ q_b,
    const u16* __restrict__ pkv, const float* __restrict__ kv_b,
    u16* __restrict__ qb, u16* __restrict__ kb, u16* __restrict__ vb) {
    __shared__ __align__(16) u16 sh[16896];   // A-tile [64][264] ∪ weight dbuf 2×8192
    const int tid = threadIdx.x, wv = tid >> 6, l = tid & 63;
    const int lj = l & 15, lg = l >> 4;
    const int blk = blockIdx.x, b = blk / 49;
    const int hwb = (blk % 49) * 64;
    const int p0 = b * HW + hwb;
    const int row0 = wv * 16;
    u16(*A)[264] = (u16(*)[264])sh;
    const float4 nw4 = *(const float4*)&n1w[4 * l];
    const float4 nb4 = *(const float4*)&n1b[4 * l];
    bfrag af1[8], af2[8];
#pragma unroll
    for (int s = 0; s < 2; ++s) {
        const float* src = s ? y2f : y1f;
        for (int tk = 0; tk < 16; ++tk) {   // LN one token per iteration (wave-private rows)
            float4 v = *(const float4*)(src + (size_t)(p0 + row0 + tk) * 256 + 4 * l);
            float sm = v.x + v.y + v.z + v.w;
            float sq = v.x * v.x + v.y * v.y + v.z * v.z + v.w * v.w;
#pragma unroll
            for (int off = 1; off < 64; off <<= 1) { sm += __shfl_xor(sm, off); sq += __shfl_xor(sq, off); }
            float mean = sm * (1.f / 256.f);
            float rstd = rsqrtf(sq * (1.f / 256.f) - mean * mean + 1e-5f);
            float a0 = (v.x - mean) * rstd * nw4.x + nb4.x, a1 = (v.y - mean) * rstd * nw4.y + nb4.y;
            float a2 = (v.z - mean) * rstd * nw4.z + nb4.z, a3 = (v.w - mean) * rstd * nw4.w + nb4.w;
            u32* dst = (u32*)&A[row0 + tk][4 * l];
            dst[0] = (u32)f2bf(a0) | ((u32)f2bf(a1) << 16);
            dst[1] = (u32)f2bf(a2) | ((u32)f2bf(a3) << 16);
        }
        if (s == 0) {
#pragma unroll
            for (int kt = 0; kt < 8; ++kt) af1[kt] = *(const bfrag*)&A[row0 + lj][kt * 32 + lg * 8];
        } else {
#pragma unroll
            for (int kt = 0; kt < 8; ++kt) af2[kt] = *(const bfrag*)&A[row0 + lj][kt * 32 + lg * 8];
        }
    }
    int rb[4];
#pragma unroll
    for (int r = 0; r < 4; ++r) {
        int hw = hwb + row0 + 4 * lg + r;
        int hh = hw / 56, ww = hw % 56;
        int win = b * 64 + (hh / 7) * 8 + (ww / 7);
        int nn = (hh % 7) * 7 + (ww % 7);
        rb[r] = (win * 49 + nn) * 256;
    }
    __syncthreads();           // all waves done reading A before weight staging reuses it

    auto stage = [&](int c, int bufsel) {
        const u16* src = (c < 8) ? pq + (size_t)c * 8192
                       : (c < 16) ? pkv + (size_t)(c - 8) * 8192
                                  : pkv + 65536 + (size_t)(c - 16) * 8192;
        u16* dbase = sh + bufsel * 8192 + wv * 512;
        const u16* gsrc = src + wv * 512 + l * 8;
#pragma unroll
        for (int r = 0; r < 4; ++r)
            gl_lds16(gsrc + r * 2048, dbase + r * 2048);
    };
    auto do_chunk = [&](int cl, const bfrag (&af)[8], const float* bias, u16* dst, const u16* WBb) {
#pragma unroll
        for (int jtl = 0; jtl < 2; ++jtl) {
            const int jt = cl * 2 + jtl;
            float bb = bias[jt * 16 + lj];
            f32x4 acc = {bb, bb, bb, bb};
#pragma unroll
            for (int kt = 0; kt < 8; ++kt)
                acc = MFMA16(af[kt], *(const bfrag*)&WBb[(jtl * 8 + kt) * 512 + l * 8], acc);
#pragma unroll
            for (int r = 0; r < 4; ++r) dst[rb[r] + jt * 16 + lj] = f2bf(acc[r]);
        }
    };

    stage(0, 0);
    __syncthreads();
    int buf = 0;
    for (int c = 0; c < 24; ++c) {
        if (c < 23) stage(c + 1, buf ^ 1);
        const u16* WBb = sh + buf * 8192;
        if (c < 8)       do_chunk(c,      af1, q_b,        qb, WBb);
        else if (c < 16) do_chunk(c - 8,  af2, kv_b,       kb, WBb);
        else             do_chunk(c - 16, af2, kv_b + 256, vb, WBb);
        __syncthreads();
        buf ^= 1;
    }
}

// ---- attention per (window, head); scores staged in LDS (no scratch spill) ----
__global__ __launch_bounds__(64) void attn_k(
    const u16* __restrict__ qb, const u16* __restrict__ kb, const u16* __restrict__ vb,
    const float* __restrict__ rel_bias, u16* __restrict__ ob) {
    __shared__ float ks[49][32];
    __shared__ float vs[49][32];
    __shared__ float bs[169];
    __shared__ float ss[49][50];
    const int win = blockIdx.x, head = blockIdx.y;
    const int lane = threadIdx.x;
    const size_t wbase = (size_t)win * 49 * 256 + head * 32;
    for (int t = lane; t < 196; t += 64) {
        int j = t >> 2, c8 = (t & 3) * 8;
        uint4 uk = *(const uint4*)(kb + wbase + (size_t)j * 256 + c8);
        uint4 uv = *(const uint4*)(vb + wbase + (size_t)j * 256 + c8);
        ks[j][c8 + 0] = bflo(uk.x); ks[j][c8 + 1] = bfhi(uk.x);
        ks[j][c8 + 2] = bflo(uk.y); ks[j][c8 + 3] = bfhi(uk.y);
        ks[j][c8 + 4] = bflo(uk.z); ks[j][c8 + 5] = bfhi(uk.z);
        ks[j][c8 + 6] = bflo(uk.w); ks[j][c8 + 7] = bfhi(uk.w);
        vs[j][c8 + 0] = bflo(uv.x); vs[j][c8 + 1] = bfhi(uv.x);
        vs[j][c8 + 2] = bflo(uv.y); vs[j][c8 + 3] = bfhi(uv.y);
        vs[j][c8 + 4] = bflo(uv.z); vs[j][c8 + 5] = bfhi(uv.z);
        vs[j][c8 + 6] = bflo(uv.w); vs[j][c8 + 7] = bfhi(uv.w);
    }
    for (int t = lane; t < 169; t += 64) bs[t] = rel_bias[t * 8 + head];
    __syncthreads();
    if (lane < 49) {
        float qr[32];
        const uint4* qrow = (const uint4*)(qb + wbase + (size_t)lane * 256);
#pragma unroll
        for (int q4 = 0; q4 < 4; ++q4) {
            uint4 u = qrow[q4];
            qr[q4 * 8 + 0] = bflo(u.x); qr[q4 * 8 + 1] = bfhi(u.x);
            qr[q4 * 8 + 2] = bflo(u.y); qr[q4 * 8 + 3] = bfhi(u.y);
            qr[q4 * 8 + 4] = bflo(u.z); qr[q4 * 8 + 5] = bfhi(u.z);
            qr[q4 * 8 + 6] = bflo(u.w); qr[q4 * 8 + 7] = bfhi(u.w);
        }
        const float scale = 0.17677669529663687f;
#pragma unroll
        for (int i = 0; i < 32; ++i) qr[i] *= scale;
        const int yi = lane / 7, xi = lane % 7;
        float mx = -1e30f;
        for (int j = 0; j < 49; ++j) {
            float dot = 0.f;
#pragma unroll
            for (int hd = 0; hd < 32; ++hd) dot += qr[hd] * ks[j][hd];
            dot += bs[(yi - j / 7 + 6) * 13 + (xi - j % 7 + 6)];
            ss[lane][j] = dot;
            mx = fmaxf(mx, dot);
        }
        float denom = 0.f;
        for (int j = 0; j < 49; ++j) { float e = __expf(ss[lane][j] - mx); ss[lane][j] = e; denom += e; }
        const float inv = 1.f / denom;
        const int bwin = win >> 6, wloc = win & 63;
        const int hh = (wloc >> 3) * 7 + yi, ww = (wloc & 7) * 7 + xi;
        u16* orow = ob + ((size_t)bwin * HW + hh * 56 + ww) * 256 + head * 32;
        for (int hd = 0; hd < 32; hd += 2) {
            float a0 = 0.f, a1 = 0.f;
            for (int j = 0; j < 49; ++j) { float p = ss[lane][j]; a0 += p * vs[j][hd]; a1 += p * vs[j][hd + 1]; }
            *(u32*)&orow[hd] = (u32)f2bf(a0 * inv) | ((u32)f2bf(a1 * inv) << 16);
        }
    }
}

// ---- proj + shortcut residual: yo = y1 + o @ proj_w.T + b; weights LDS-staged (dbuf) ----
__global__ __launch_bounds__(256) void proj_k(
    const u16* __restrict__ obuf, const u16* __restrict__ pp,
    const float* __restrict__ proj_b, const float* __restrict__ y1f,
    float* __restrict__ yo) {
    __shared__ __align__(16) u16 sh[16896];   // A-tile [64][264] ∪ weight dbuf 2×8192
    const int tid = threadIdx.x, wv = tid >> 6, l = tid & 63;
    const int lj = l & 15, lg = l >> 4;
    const int blk = blockIdx.x, b = blk / 49;
    const int p0 = b * HW + (blk % 49) * 64;
    const int row0 = wv * 16;
    u16(*A)[264] = (u16(*)[264])sh;
#pragma unroll
    for (int t = 0; t < 8; ++t) {
        int rr = row0 + t * 2 + (l >> 5);
        *(uint4*)&A[rr][(l & 31) * 8] = *(const uint4*)(obuf + (size_t)(p0 + rr) * 256 + (l & 31) * 8);
    }
    bfrag af[8];
#pragma unroll
    for (int kt = 0; kt < 8; ++kt) af[kt] = *(const bfrag*)&A[row0 + lj][kt * 32 + lg * 8];
    __syncthreads();           // all waves done reading A before weight staging reuses it

    auto stage = [&](int c, int bufsel) {
        const u16* gsrc = pp + (size_t)c * 8192 + wv * 512 + l * 8;
        u16* dbase = sh + bufsel * 8192 + wv * 512;
#pragma unroll
        for (int r = 0; r < 4; ++r)
            gl_lds16(gsrc + r * 2048, dbase + r * 2048);
    };
    stage(0, 0);
    __syncthreads();
    int buf = 0;
#pragma unroll
    for (int c = 0; c < 8; ++c) {
        if (c < 7) stage(c + 1, buf ^ 1);
        const u16* WBb = sh + buf * 8192;
#pragma unroll
        for (int jtl = 0; jtl < 2; ++jtl) {
            const int jt = c * 2 + jtl;
            float bb = proj_b[jt * 16 + lj];
            f32x4 acc = {bb, bb, bb, bb};
#pragma unroll
            for (int kt = 0; kt < 8; ++kt)
                acc = MFMA16(af[kt], *(const bfrag*)&WBb[(jtl * 8 + kt) * 512 + l * 8], acc);
#pragma unroll
            for (int r = 0; r < 4; ++r) {
                size_t ad = (size_t)(p0 + row0 + 4 * lg + r) * 256 + jt * 16 + lj;
                yo[ad] = acc[r] + y1f[ad];
            }
        }
        __syncthreads();
        buf ^= 1;
    }
}

// ---- token-major -> NCHW transpose of yo (residual source for mlp epilogue) ----
__global__ __launch_bounds__(256) void t2n_k(const float* __restrict__ yo, float* __restrict__ yn) {
    __shared__ float T[4][16][68];
    const int tid = threadIdx.x, w = tid >> 6, l = tid & 63;
    const int lj = l & 15, lg = l >> 4;
    const int blk = blockIdx.x, b = blk / 49;
    const int hwb = (blk % 49) * 64 + w * 16;
    const int c0 = blockIdx.y * 64;
    for (int tk = 0; tk < 16; ++tk)
        T[w][tk][l] = yo[(size_t)(b * HW + hwb + tk) * 256 + c0 + l];
    __syncthreads();
    for (int cc = 0; cc < 16; ++cc) {
        int c = c0 + cc * 4 + lg;
        yn[((size_t)b * 256 + c) * HW + hwb + lj] = T[w][lj][cc * 4 + lg];
    }
}

// ---- n2-LN + fc1 + tanh-GELU + fc2; weights LDS-staged (dbuf) per 32-h chunk ----
__global__ __launch_bounds__(256) void mlp_k(
    const float* __restrict__ yo, const float* __restrict__ yn,
    const float* __restrict__ n2w, const float* __restrict__ n2b,
    const u16* __restrict__ pf1, const float* __restrict__ fc1_b,
    const u16* __restrict__ pf2, const float* __restrict__ fc2_b,
    float* __restrict__ out) {
    __shared__ __align__(16) u16 sh[32768];   // A-tile [64][264] ∪ weight dbuf 2×16384
    __shared__ __align__(16) u16 Hs[64][40];  // GELU'd h chunk (transpose buffer)
    const int tid = threadIdx.x, wv = tid >> 6, l = tid & 63;
    const int lj = l & 15, lg = l >> 4;
    const int blk = blockIdx.x, b = blk / 49;
    const int hwb = (blk % 49) * 64;
    const int p0 = b * HW + hwb;
    const int row0 = wv * 16;
    u16(*A)[264] = (u16(*)[264])sh;
    {   // stage + n2 LayerNorm (wave-private rows)
        const float4 nw4 = *(const float4*)&n2w[4 * l];
        const float4 nb4 = *(const float4*)&n2b[4 * l];
        for (int tk = 0; tk < 16; ++tk) {
            float4 v = *(const float4*)(yo + (size_t)(p0 + row0 + tk) * 256 + 4 * l);
            float sm = v.x + v.y + v.z + v.w;
            float sq = v.x * v.x + v.y * v.y + v.z * v.z + v.w * v.w;
#pragma unroll
            for (int off = 1; off < 64; off <<= 1) { sm += __shfl_xor(sm, off); sq += __shfl_xor(sq, off); }
            float mean = sm * (1.f / 256.f);
            float rstd = rsqrtf(sq * (1.f / 256.f) - mean * mean + 1e-5f);
            float a0 = (v.x - mean) * rstd * nw4.x + nb4.x, a1 = (v.y - mean) * rstd * nw4.y + nb4.y;
            float a2 = (v.z - mean) * rstd * nw4.z + nb4.z, a3 = (v.w - mean) * rstd * nw4.w + nb4.w;
            u32* dst = (u32*)&A[row0 + tk][4 * l];
            dst[0] = (u32)f2bf(a0) | ((u32)f2bf(a1) << 16);
            dst[1] = (u32)f2bf(a2) | ((u32)f2bf(a3) << 16);
        }
    }
    bfrag af[8];
#pragma unroll
    for (int kt = 0; kt < 8; ++kt) af[kt] = *(const bfrag*)&A[row0 + lj][kt * 32 + lg * 8];
    f32x4 acc2[16];
#pragma unroll
    for (int jt = 0; jt < 16; ++jt) acc2[jt] = *(const f32x4*)&fc2_b[jt * 16 + 4 * lg];
    __syncthreads();           // all waves done reading A before weight staging reuses it

    auto stage = [&](int c, int bufsel) {
        const u16* s1 = pf1 + (size_t)c * 8192;
        const u16* s2 = pf2 + (size_t)c * 8192;
        u16* dbase = sh + bufsel * 16384 + wv * 512;
        const int goff = wv * 512 + l * 8;
#pragma unroll
        for (int r = 0; r < 4; ++r) {
            gl_lds16(s1 + r * 2048 + goff, dbase + r * 2048);
            gl_lds16(s2 + r * 2048 + goff, dbase + 8192 + r * 2048);
        }
    };

    stage(0, 0);
    __syncthreads();
    int buf = 0;
    for (int c = 0; c < 32; ++c) {
        if (c < 31) stage(c + 1, buf ^ 1);
        const u16* WBb = sh + buf * 16384;
        // fc1: 2 jt-tiles (32 h-cols) + tanh-GELU -> Hs
#pragma unroll
        for (int jtl = 0; jtl < 2; ++jtl) {
            float hb = fc1_b[c * 32 + jtl * 16 + lj];
            f32x4 a1 = {hb, hb, hb, hb};
#pragma unroll
            for (int kt = 0; kt < 8; ++kt)
                a1 = MFMA16(af[kt], *(const bfrag*)&WBb[(jtl * 8 + kt) * 512 + l * 8], a1);
#pragma unroll
            for (int r = 0; r < 4; ++r) {
                float xv = a1[r];
                float uu = 0.7978845608028654f * xv * (1.0f + 0.044715f * xv * xv);
                uu = fminf(fmaxf(uu, -9.0f), 9.0f);
                float e2 = __expf(2.0f * uu);
                float g = 0.5f * xv * (1.0f + (e2 - 1.0f) / (e2 + 1.0f));
                float gn = __shfl_down(g, 1);
                if (!(l & 1))
                    *(u32*)&Hs[row0 + 4 * lg + r][jtl * 16 + (lj & 14)] = (u32)f2bf(g) | ((u32)f2bf(gn) << 16);
            }
        }
        // fc2 partial for this 32-h k-slice (swapped operands -> D[n][token])
        bfrag hf = *(const bfrag*)&Hs[row0 + lj][lg * 8];
#pragma unroll
        for (int jt = 0; jt < 16; ++jt)
            acc2[jt] = MFMA16(*(const bfrag*)&WBb[8192 + jt * 512 + l * 8], hf, acc2[jt]);
        __syncthreads();
        buf ^= 1;
    }
    const size_t obase = (size_t)b * 256 * HW + hwb + row0 + lj;
#pragma unroll
    for (int jt = 0; jt < 16; ++jt)
#pragma unroll
        for (int r = 0; r < 4; ++r) {
            size_t ad = obase + (size_t)(jt * 16 + 4 * lg + r) * HW;
            out[ad] = yn[ad] + acc2[jt][r];
        }
}

extern "C" void kernel_launch(void* const* d_in, const int* in_sizes, int n_in,
                              void* d_out, int out_size, void* d_ws, size_t ws_size,
                              hipStream_t stream) {
    const float* x1      = (const float*)d_in[0];
    const float* x2      = (const float*)d_in[1];
    const float* pe_w    = (const float*)d_in[2];
    const float* pe_b    = (const float*)d_in[3];
    const float* pe_ln_w = (const float*)d_in[4];
    const float* pe_ln_b = (const float*)d_in[5];
    const float* n1_w    = (const float*)d_in[6];
    const float* n1_b    = (const float*)d_in[7];
    const float* q_w     = (const float*)d_in[8];
    const float* q_b     = (const float*)d_in[9];
    const float* kv_w    = (const float*)d_in[10];
    const float* kv_b    = (const float*)d_in[11];
    const float* rel_bias= (const float*)d_in[12];
    const float* proj_w  = (const float*)d_in[13];
    const float* proj_b  = (const float*)d_in[14];
    const float* n2_w    = (const float*)d_in[15];
    const float* n2_b    = (const float*)d_in[16];
    const float* fc1_w   = (const float*)d_in[17];
    const float* fc1_b   = (const float*)d_in[18];
    const float* fc2_w   = (const float*)d_in[19];
    const float* fc2_b   = (const float*)d_in[20];
    float* out = (float*)d_out;

    float* ws = (float*)d_ws;
    const size_t NTC = (size_t)50176 * 256;
    float* y1 = ws;                 // embed(x1); shortcut
    float* y2 = y1 + NTC;           // embed(x2); reused as yo (post-proj y)
    float* yn = y2 + NTC;           // yo in NCHW layout
    u16* qb   = (u16*)(yn + NTC);
    u16* kb   = qb + NTC;
    u16* vb   = kb + NTC;
    u16* obuf = vb + NTC;
    u16* ppe  = obuf + NTC;
    u16* pq   = ppe + 65536;
    u16* pkv  = pq + 65536;
    u16* pproj= pkv + 131072;
    u16* pf1  = pproj + 65536;
    u16* pf2  = pf1 + 262144;

    pack_jt_k<<<128, 64, 0, stream>>>(pe_w,  ppe,   256, 8);   // jt-major (staged)
    pack_jt_k<<<128, 64, 0, stream>>>(q_w,   pq,    256, 8);   // jt-major (staged)
    pack_jt_k<<<256, 64, 0, stream>>>(kv_w,  pkv,   256, 8);   // jt-major (staged)
    pack_jt_k<<<128, 64, 0, stream>>>(proj_w,pproj, 256, 8);   // jt-major (staged)
    pack_jt_k<<<512, 64, 0, stream>>>(fc1_w, pf1,   256, 8);   // jt-major (staged)
    pack_k  <<<512, 64, 0, stream>>>(fc2_w, pf2,  1024, 16);   // kt-major == per-k-tile chunks

    embed_k<<<dim3(784, 2), 256, 0, stream>>>(x1, x2, ppe, pe_b, pe_ln_w, pe_ln_b, y1, y2);
    qkv_k<<<784, 256, 0, stream>>>(y1, y2, n1_w, n1_b, pq, q_b, pkv, kv_b, qb, kb, vb);
    attn_k<<<dim3(1024, 8), 64, 0, stream>>>(qb, kb, vb, rel_bias, obuf);
    proj_k<<<784, 256, 0, stream>>>(obuf, pproj, proj_b, y1, y2);
    t2n_k<<<dim3(784, 4), 256, 0, stream>>>(y2, yn);
    mlp_k<<<784, 256, 0, stream>>>(y2, yn, n2_w, n2_b, pf1, fc1_b, pf2, fc2_b, out);
}

// Round 6
// 682.258 us; speedup vs baseline: 3.5472x; 1.0091x over previous
//
#include <hip/hip_runtime.h>
#include <math.h>

#define HW 3136
typedef unsigned short u16;
typedef unsigned int u32;
typedef __attribute__((ext_vector_type(8))) short bfrag;   // 8 bf16 (4 VGPRs)
typedef __attribute__((ext_vector_type(4))) float f32x4;   // MFMA accumulator

#define MFMA16(A, B, C) __builtin_amdgcn_mfma_f32_16x16x32_bf16(A, B, C, 0, 0, 0)

__device__ __forceinline__ u16 f2bf(float f) {            // RNE float->bf16
    u32 u = __builtin_bit_cast(u32, f);
    u = (u + 0x7fffu + ((u >> 16) & 1u)) >> 16;
    return (u16)u;
}
__device__ __forceinline__ float bflo(u32 v) { return __builtin_bit_cast(float, v << 16); }
__device__ __forceinline__ float bfhi(u32 v) { return __builtin_bit_cast(float, v & 0xffff0000u); }

typedef __attribute__((address_space(1))) const unsigned int g_u32;
typedef __attribute__((address_space(3))) unsigned int l_u32;
__device__ __forceinline__ void gl_lds16(const u16* g, u16* l) {
    // async global->LDS, 16B per lane; LDS dest = wave-uniform base + lane*16
    __builtin_amdgcn_global_load_lds((g_u32*)g, (l_u32*)l, 16, 0, 0);
}

// ---- pack W [N][K] fp32 into MFMA fragment order, kt-major tiles (tile = kt*NT + jt) ----
__global__ void pack_k(const float* __restrict__ W, u16* __restrict__ out, int K, int NT) {
    const int tile = blockIdx.x, l = threadIdx.x;
    const int kt = tile / NT, jt = tile % NT;
    const int n = jt * 16 + (l & 15);
    const int k0 = kt * 32 + (l >> 4) * 8;
    const float* src = W + (size_t)n * K + k0;
    float4 s0 = *(const float4*)src;
    float4 s1 = *(const float4*)(src + 4);
    uint4 u;
    u.x = (u32)f2bf(s0.x) | ((u32)f2bf(s0.y) << 16);
    u.y = (u32)f2bf(s0.z) | ((u32)f2bf(s0.w) << 16);
    u.z = (u32)f2bf(s1.x) | ((u32)f2bf(s1.y) << 16);
    u.w = (u32)f2bf(s1.z) | ((u32)f2bf(s1.w) << 16);
    *(uint4*)(out + ((size_t)tile * 64 + l) * 8) = u;
}

// ---- pack, jt-major tiles (tile = jt*KT + kt) -> per-jt chunks contiguous for LDS staging ----
__global__ void pack_jt_k(const float* __restrict__ W, u16* __restrict__ out, int K, int KT) {
    const int tile = blockIdx.x, l = threadIdx.x;
    const int jt = tile / KT, kt = tile % KT;
    const int n = jt * 16 + (l & 15);
    const int k0 = kt * 32 + (l >> 4) * 8;
    const float* src = W + (size_t)n * K + k0;
    float4 s0 = *(const float4*)src;
    float4 s1 = *(const float4*)(src + 4);
    uint4 u;
    u.x = (u32)f2bf(s0.x) | ((u32)f2bf(s0.y) << 16);
    u.y = (u32)f2bf(s0.z) | ((u32)f2bf(s0.w) << 16);
    u.z = (u32)f2bf(s1.x) | ((u32)f2bf(s1.y) << 16);
    u.w = (u32)f2bf(s1.z) | ((u32)f2bf(s1.w) << 16);
    *(uint4*)(out + ((size_t)tile * 64 + l) * 8) = u;
}

// ---- embed: y = LN(pe_w @ x + pe_b); weights LDS-staged (dbuf), A-frags from NCHW x ----
__global__ __launch_bounds__(256) void embed_k(
    const float* __restrict__ x1, const float* __restrict__ x2,
    const u16* __restrict__ wp, const float* __restrict__ pe_b,
    const float* __restrict__ lnw, const float* __restrict__ lnb,
    float* __restrict__ y1, float* __restrict__ y2) {
    __shared__ __align__(16) u16 sh[2][8192];   // weight dbuf, 2 x 16KB (2 jt-tiles each)
    const float* x = blockIdx.y ? x2 : x1;
    float* y = blockIdx.y ? y2 : y1;
    const int tid = threadIdx.x, wv = tid >> 6, l = tid & 63;
    const int lj = l & 15, lg = l >> 4;
    const int blk = blockIdx.x, b = blk / 49;
    const int hw0 = (blk % 49) * 64 + wv * 16;     // wave's 16 tokens
    const float* xb = x + (size_t)b * 256 * HW + hw0 + lj;
    bfrag af[8];
#pragma unroll
    for (int kt = 0; kt < 8; ++kt)
#pragma unroll
        for (int bb = 0; bb < 8; ++bb)
            af[kt][bb] = (short)f2bf(xb[(size_t)(kt * 32 + lg * 8 + bb) * HW]);
    f32x4 acc[16];
#pragma unroll
    for (int jt = 0; jt < 16; ++jt) { float bb = pe_b[jt * 16 + lj]; f32x4 t = {bb, bb, bb, bb}; acc[jt] = t; }

    auto stage = [&](int c, int bufsel) {
        const u16* gsrc = wp + (size_t)c * 8192 + wv * 512 + l * 8;
        u16* dbase = &sh[bufsel][wv * 512];
#pragma unroll
        for (int r = 0; r < 4; ++r)
            gl_lds16(gsrc + r * 2048, dbase + r * 2048);
    };
    stage(0, 0);
    __syncthreads();
    int buf = 0;
#pragma unroll
    for (int c = 0; c < 8; ++c) {
        if (c < 7) stage(c + 1, buf ^ 1);
        const u16* WBb = sh[buf];
#pragma unroll
        for (int jtl = 0; jtl < 2; ++jtl) {
            const int jt = c * 2 + jtl;
#pragma unroll
            for (int kt = 0; kt < 8; ++kt)
                acc[jt] = MFMA16(af[kt], *(const bfrag*)&WBb[(jtl * 8 + kt) * 512 + l * 8], acc[jt]);
        }
        __syncthreads();
        buf ^= 1;
    }
    // LayerNorm: token row = 4*lg + r lives in this lane's 16-lane group
    float sum[4] = {0, 0, 0, 0}, sq[4] = {0, 0, 0, 0};
#pragma unroll
    for (int jt = 0; jt < 16; ++jt)
#pragma unroll
        for (int r = 0; r < 4; ++r) { float v = acc[jt][r]; sum[r] += v; sq[r] += v * v; }
#pragma unroll
    for (int r = 0; r < 4; ++r)
#pragma unroll
        for (int off = 1; off < 16; off <<= 1) { sum[r] += __shfl_xor(sum[r], off); sq[r] += __shfl_xor(sq[r], off); }
    const int p0 = b * HW + hw0;
#pragma unroll
    for (int r = 0; r < 4; ++r) {
        float mean = sum[r] * (1.f / 256.f);
        float rstd = rsqrtf(sq[r] * (1.f / 256.f) - mean * mean + 1e-5f);
        float* yrow = y + (size_t)(p0 + 4 * lg + r) * 256;
#pragma unroll
        for (int jt = 0; jt < 16; ++jt) {
            int c = jt * 16 + lj;
            yrow[c] = (acc[jt][r] - mean) * rstd * lnw[c] + lnb[c];
        }
    }
}

// ---- n1-LN + q/k/v projections; weights LDS-staged (dbuf) & shared across waves ----
__global__ __launch_bounds__(256) void qkv_k(
    const float* __restrict__ y1f, const float* __restrict__ y2f,
    const float* __restrict__ n1w, const float* __restrict__ n1b,
    const u16* __restrict__ pq, const float* __restrict__ q_b,
    const u16* __restrict__ pkv, const float* __restrict__ kv_b,
    u16* __restrict__ qb, u16* __restrict__ kb, u16* __restrict__ vb) {
    __shared__ __align__(16) u16 sh[16896];   // A-tile [64][264] ∪ weight dbuf 2×8192
    const int tid = threadIdx.x, wv = tid >> 6, l = tid & 63;
    const int lj = l & 15, lg = l >> 4;
    const int blk = blockIdx.x, b = blk / 49;
    const int hwb = (blk % 49) * 64;
    const int p0 = b * HW + hwb;
    const int row0 = wv * 16;
    u16(*A)[264] = (u16(*)[264])sh;
    const float4 nw4 = *(const float4*)&n1w[4 * l];
    const float4 nb4 = *(const float4*)&n1b[4 * l];
    bfrag af1[8], af2[8];
#pragma unroll
    for (int s = 0; s < 2; ++s) {
        const float* src = s ? y2f : y1f;
        for (int tk = 0; tk < 16; ++tk) {   // LN one token per iteration (wave-private rows)
            float4 v = *(const float4*)(src + (size_t)(p0 + row0 + tk) * 256 + 4 * l);
            float sm = v.x + v.y + v.z + v.w;
            float sq = v.x * v.x + v.y * v.y + v.z * v.z + v.w * v.w;
#pragma unroll
            for (int off = 1; off < 64; off <<= 1) { sm += __shfl_xor(sm, off); sq += __shfl_xor(sq, off); }
            float mean = sm * (1.f / 256.f);
            float rstd = rsqrtf(sq * (1.f / 256.f) - mean * mean + 1e-5f);
            float a0 = (v.x - mean) * rstd * nw4.x + nb4.x, a1 = (v.y - mean) * rstd * nw4.y + nb4.y;
            float a2 = (v.z - mean) * rstd * nw4.z + nb4.z, a3 = (v.w - mean) * rstd * nw4.w + nb4.w;
            u32* dst = (u32*)&A[row0 + tk][4 * l];
            dst[0] = (u32)f2bf(a0) | ((u32)f2bf(a1) << 16);
            dst[1] = (u32)f2bf(a2) | ((u32)f2bf(a3) << 16);
        }
        if (s == 0) {
#pragma unroll
            for (int kt = 0; kt < 8; ++kt) af1[kt] = *(const bfrag*)&A[row0 + lj][kt * 32 + lg * 8];
        } else {
#pragma unroll
            for (int kt = 0; kt < 8; ++kt) af2[kt] = *(const bfrag*)&A[row0 + lj][kt * 32 + lg * 8];
        }
    }
    int rb[4];
#pragma unroll
    for (int r = 0; r < 4; ++r) {
        int hw = hwb + row0 + 4 * lg + r;
        int hh = hw / 56, ww = hw % 56;
        int win = b * 64 + (hh / 7) * 8 + (ww / 7);
        int nn = (hh % 7) * 7 + (ww % 7);
        rb[r] = (win * 49 + nn) * 256;
    }
    __syncthreads();           // all waves done reading A before weight staging reuses it

    auto stage = [&](int c, int bufsel) {
        const u16* src = (c < 8) ? pq + (size_t)c * 8192
                       : (c < 16) ? pkv + (size_t)(c - 8) * 8192
                                  : pkv + 65536 + (size_t)(c - 16) * 8192;
        u16* dbase = sh + bufsel * 8192 + wv * 512;
        const u16* gsrc = src + wv * 512 + l * 8;
#pragma unroll
        for (int r = 0; r < 4; ++r)
            gl_lds16(gsrc + r * 2048, dbase + r * 2048);
    };
    auto do_chunk = [&](int cl, const bfrag (&af)[8], const float* bias, u16* dst, const u16* WBb) {
#pragma unroll
        for (int jtl = 0; jtl < 2; ++jtl) {
            const int jt = cl * 2 + jtl;
            float bb = bias[jt * 16 + lj];
            f32x4 acc = {bb, bb, bb, bb};
#pragma unroll
            for (int kt = 0; kt < 8; ++kt)
                acc = MFMA16(af[kt], *(const bfrag*)&WBb[(jtl * 8 + kt) * 512 + l * 8], acc);
#pragma unroll
            for (int r = 0; r < 4; ++r) dst[rb[r] + jt * 16 + lj] = f2bf(acc[r]);
        }
    };

    stage(0, 0);
    __syncthreads();
    int buf = 0;
    for (int c = 0; c < 24; ++c) {
        if (c < 23) stage(c + 1, buf ^ 1);
        const u16* WBb = sh + buf * 8192;
        if (c < 8)       do_chunk(c,      af1, q_b,        qb, WBb);
        else if (c < 16) do_chunk(c - 8,  af2, kv_b,       kb, WBb);
        else             do_chunk(c - 16, af2, kv_b + 256, vb, WBb);
        __syncthreads();
        buf ^= 1;
    }
}

// ---- attention: block = (window, 4 heads); one wave per head, barrier-free ----
__global__ __launch_bounds__(256) void attn_k(
    const u16* __restrict__ qb, const u16* __restrict__ kb, const u16* __restrict__ vb,
    const float* __restrict__ rel_bias, u16* __restrict__ ob) {
    __shared__ __align__(16) u16 ks[4][49][32];
    __shared__ __align__(16) u16 vs[4][49][32];
    __shared__ float bsh[4][169];
    const int tid = threadIdx.x, wv = tid >> 6, l = tid & 63;
    const int win = blockIdx.x;
    const int head = blockIdx.y * 4 + wv;
    const size_t wbase = (size_t)win * 49 * 256 + head * 32;
    for (int t = l; t < 196; t += 64) {       // 49 rows x 4 segs of 8 u16
        int j = t >> 2, sg = (t & 3) * 8;
        *(uint4*)&ks[wv][j][sg] = *(const uint4*)(kb + wbase + (size_t)j * 256 + sg);
        *(uint4*)&vs[wv][j][sg] = *(const uint4*)(vb + wbase + (size_t)j * 256 + sg);
    }
    for (int t = l; t < 169; t += 64) bsh[wv][t] = rel_bias[t * 8 + head];
    // no __syncthreads: all LDS regions are wave-private (in-wave lgkmcnt ordering)
    if (l < 49) {
        float qr[32];
        const uint4* qrow = (const uint4*)(qb + wbase + (size_t)l * 256);
#pragma unroll
        for (int q4 = 0; q4 < 4; ++q4) {
            uint4 u = qrow[q4];
            qr[q4 * 8 + 0] = bflo(u.x); qr[q4 * 8 + 1] = bfhi(u.x);
            qr[q4 * 8 + 2] = bflo(u.y); qr[q4 * 8 + 3] = bfhi(u.y);
            qr[q4 * 8 + 4] = bflo(u.z); qr[q4 * 8 + 5] = bfhi(u.z);
            qr[q4 * 8 + 6] = bflo(u.w); qr[q4 * 8 + 7] = bfhi(u.w);
        }
        const float scale = 0.17677669529663687f;
#pragma unroll
        for (int i = 0; i < 32; ++i) qr[i] *= scale;
        const int yi = l / 7, xi = l % 7;
        float s[49];
        float mx = -1e30f;
#pragma unroll
        for (int j = 0; j < 49; ++j) {
            float dot = 0.f;
#pragma unroll
            for (int h2 = 0; h2 < 16; ++h2) {
                u32 kk = *(const u32*)&ks[wv][j][h2 * 2];
                dot += qr[h2 * 2] * bflo(kk) + qr[h2 * 2 + 1] * bfhi(kk);
            }
            dot += bsh[wv][(yi - j / 7 + 6) * 13 + (xi - j % 7 + 6)];
            s[j] = dot;
            mx = fmaxf(mx, dot);
        }
        float denom = 0.f;
#pragma unroll
        for (int j = 0; j < 49; ++j) { float e = __expf(s[j] - mx); s[j] = e; denom += e; }
        const float inv = 1.f / denom;
        const int bwin = win >> 6, wloc = win & 63;
        const int hh = (wloc >> 3) * 7 + yi, ww = (wloc & 7) * 7 + xi;
        u16* orow = ob + ((size_t)bwin * HW + hh * 56 + ww) * 256 + head * 32;
        for (int hp = 0; hp < 16; ++hp) {
            float a0 = 0.f, a1 = 0.f;
#pragma unroll
            for (int j = 0; j < 49; ++j) {
                u32 vv = *(const u32*)&vs[wv][j][hp * 2];
                a0 += s[j] * bflo(vv); a1 += s[j] * bfhi(vv);
            }
            *(u32*)&orow[hp * 2] = (u32)f2bf(a0 * inv) | ((u32)f2bf(a1 * inv) << 16);
        }
    }
}

// ---- proj + shortcut residual: yo = y1 + o @ proj_w.T + b; weights LDS-staged (dbuf) ----
__global__ __launch_bounds__(256) void proj_k(
    const u16* __restrict__ obuf, const u16* __restrict__ pp,
    const float* __restrict__ proj_b, const float* __restrict__ y1f,
    float* __restrict__ yo) {
    __shared__ __align__(16) u16 sh[16896];   // A-tile [64][264] ∪ weight dbuf 2×8192
    const int tid = threadIdx.x, wv = tid >> 6, l = tid & 63;
    const int lj = l & 15, lg = l >> 4;
    const int blk = blockIdx.x, b = blk / 49;
    const int p0 = b * HW + (blk % 49) * 64;
    const int row0 = wv * 16;
    u16(*A)[264] = (u16(*)[264])sh;
#pragma unroll
    for (int t = 0; t < 8; ++t) {
        int rr = row0 + t * 2 + (l >> 5);
        *(uint4*)&A[rr][(l & 31) * 8] = *(const uint4*)(obuf + (size_t)(p0 + rr) * 256 + (l & 31) * 8);
    }
    bfrag af[8];
#pragma unroll
    for (int kt = 0; kt < 8; ++kt) af[kt] = *(const bfrag*)&A[row0 + lj][kt * 32 + lg * 8];
    __syncthreads();           // all waves done reading A before weight staging reuses it

    auto stage = [&](int c, int bufsel) {
        const u16* gsrc = pp + (size_t)c * 8192 + wv * 512 + l * 8;
        u16* dbase = sh + bufsel * 8192 + wv * 512;
#pragma unroll
        for (int r = 0; r < 4; ++r)
            gl_lds16(gsrc + r * 2048, dbase + r * 2048);
    };
    stage(0, 0);
    __syncthreads();
    int buf = 0;
#pragma unroll
    for (int c = 0; c < 8; ++c) {
        if (c < 7) stage(c + 1, buf ^ 1);
        const u16* WBb = sh + buf * 8192;
#pragma unroll
        for (int jtl = 0; jtl < 2; ++jtl) {
            const int jt = c * 2 + jtl;
            float bb = proj_b[jt * 16 + lj];
            f32x4 acc = {bb, bb, bb, bb};
#pragma unroll
            for (int kt = 0; kt < 8; ++kt)
                acc = MFMA16(af[kt], *(const bfrag*)&WBb[(jtl * 8 + kt) * 512 + l * 8], acc);
#pragma unroll
            for (int r = 0; r < 4; ++r) {
                size_t ad = (size_t)(p0 + row0 + 4 * lg + r) * 256 + jt * 16 + lj;
                yo[ad] = acc[r] + y1f[ad];
            }
        }
        __syncthreads();
        buf ^= 1;
    }
}

// ---- n2-LN + fc1 + GELU + fc2; fc1 LDS-dbuf, fc2 frags direct from L2; residual gathered ----
__global__ __launch_bounds__(256) void mlp_k(
    const float* __restrict__ yo,
    const float* __restrict__ n2w, const float* __restrict__ n2b,
    const u16* __restrict__ pf1, const float* __restrict__ fc1_b,
    const u16* __restrict__ pf2, const float* __restrict__ fc2_b,
    float* __restrict__ out) {
    __shared__ __align__(16) u16 sh[16896];    // A-tile [64][264] ∪ fc1 dbuf 2×8192 u16
    __shared__ __align__(16) u16 Hs[64][36];   // GELU'd h chunk (pad 36 -> conflict-free)
    const int tid = threadIdx.x, wv = tid >> 6, l = tid & 63;
    const int lj = l & 15, lg = l >> 4;
    const int blk = blockIdx.x, b = blk / 49;
    const int hwb = (blk % 49) * 64;
    const int p0 = b * HW + hwb;
    const int row0 = wv * 16;
    u16(*A)[264] = (u16(*)[264])sh;
    {   // stage + n2 LayerNorm (wave-private rows)
        const float4 nw4 = *(const float4*)&n2w[4 * l];
        const float4 nb4 = *(const float4*)&n2b[4 * l];
        for (int tk = 0; tk < 16; ++tk) {
            float4 v = *(const float4*)(yo + (size_t)(p0 + row0 + tk) * 256 + 4 * l);
            float sm = v.x + v.y + v.z + v.w;
            float sq = v.x * v.x + v.y * v.y + v.z * v.z + v.w * v.w;
#pragma unroll
            for (int off = 1; off < 64; off <<= 1) { sm += __shfl_xor(sm, off); sq += __shfl_xor(sq, off); }
            float mean = sm * (1.f / 256.f);
            float rstd = rsqrtf(sq * (1.f / 256.f) - mean * mean + 1e-5f);
            float a0 = (v.x - mean) * rstd * nw4.x + nb4.x, a1 = (v.y - mean) * rstd * nw4.y + nb4.y;
            float a2 = (v.z - mean) * rstd * nw4.z + nb4.z, a3 = (v.w - mean) * rstd * nw4.w + nb4.w;
            u32* dst = (u32*)&A[row0 + tk][4 * l];
            dst[0] = (u32)f2bf(a0) | ((u32)f2bf(a1) << 16);
            dst[1] = (u32)f2bf(a2) | ((u32)f2bf(a3) << 16);
        }
    }
    bfrag af[8];    // own rows -> no barrier needed before extraction
#pragma unroll
    for (int kt = 0; kt < 8; ++kt) af[kt] = *(const bfrag*)&A[row0 + lj][kt * 32 + lg * 8];
    f32x4 acc2[16];
#pragma unroll
    for (int jt = 0; jt < 16; ++jt) acc2[jt] = *(const f32x4*)&fc2_b[jt * 16 + 4 * lg];
    __syncthreads();           // all waves done with A before fc1 staging reuses the region

    auto stage = [&](int c, int bufsel) {
        const u16* gsrc = pf1 + (size_t)c * 8192 + wv * 512 + l * 8;
        u16* dbase = sh + bufsel * 8192 + wv * 512;
#pragma unroll
        for (int r = 0; r < 4; ++r)
            gl_lds16(gsrc + r * 2048, dbase + r * 2048);
    };

    stage(0, 0);
    __syncthreads();
    int cur = 0;
    for (int c = 0; c < 32; ++c) {
        if (c < 31) stage(c + 1, cur ^ 1);
        const u16* WBb = sh + cur * 8192;
        // fc1: 2 jt-tiles (32 h-cols) + erf-GELU -> Hs
#pragma unroll
        for (int jtl = 0; jtl < 2; ++jtl) {
            float hb = fc1_b[c * 32 + jtl * 16 + lj];
            f32x4 a1 = {hb, hb, hb, hb};
#pragma unroll
            for (int kt = 0; kt < 8; ++kt)
                a1 = MFMA16(af[kt], *(const bfrag*)&WBb[(jtl * 8 + kt) * 512 + l * 8], a1);
#pragma unroll
            for (int r = 0; r < 4; ++r) {
                float xv = a1[r];
                float g = 0.5f * xv * (1.f + erff(xv * 0.70710678118654752f));
                float gn = __shfl_down(g, 1);
                if (!(l & 1))
                    *(u32*)&Hs[row0 + 4 * lg + r][jtl * 16 + (lj & 14)] = (u32)f2bf(g) | ((u32)f2bf(gn) << 16);
            }
        }
        // fc2 partial for this 32-h k-slice; W2 frags direct from global (L2-hot, coalesced)
        bfrag hf = *(const bfrag*)&Hs[row0 + lj][lg * 8];
        const u16* w2c = pf2 + (size_t)c * 8192 + l * 8;
#pragma unroll
        for (int q = 0; q < 4; ++q) {
            bfrag w0 = *(const bfrag*)(w2c + (q * 4 + 0) * 512);
            bfrag w1 = *(const bfrag*)(w2c + (q * 4 + 1) * 512);
            bfrag w2 = *(const bfrag*)(w2c + (q * 4 + 2) * 512);
            bfrag w3 = *(const bfrag*)(w2c + (q * 4 + 3) * 512);
            acc2[q * 4 + 0] = MFMA16(w0, hf, acc2[q * 4 + 0]);
            acc2[q * 4 + 1] = MFMA16(w1, hf, acc2[q * 4 + 1]);
            acc2[q * 4 + 2] = MFMA16(w2, hf, acc2[q * 4 + 2]);
            acc2[q * 4 + 3] = MFMA16(w3, hf, acc2[q * 4 + 3]);
        }
        __syncthreads();
        cur ^= 1;
    }
    // epilogue: residual gathered from token-major yo; NCHW coalesced store (lanes = tokens)
    const size_t obase = (size_t)b * 256 * HW + hwb + row0 + lj;
    const float* yrow = yo + (size_t)(p0 + row0 + lj) * 256 + 4 * lg;
#pragma unroll
    for (int jt = 0; jt < 16; ++jt) {
        float4 yv = *(const float4*)&yrow[jt * 16];
        const float* yp = (const float*)&yv;
#pragma unroll
        for (int r = 0; r < 4; ++r) {
            size_t ad = obase + (size_t)(jt * 16 + 4 * lg + r) * HW;
            out[ad] = yp[r] + acc2[jt][r];
        }
    }
}

extern "C" void kernel_launch(void* const* d_in, const int* in_sizes, int n_in,
                              void* d_out, int out_size, void* d_ws, size_t ws_size,
                              hipStream_t stream) {
    const float* x1      = (const float*)d_in[0];
    const float* x2      = (const float*)d_in[1];
    const float* pe_w    = (const float*)d_in[2];
    const float* pe_b    = (const float*)d_in[3];
    const float* pe_ln_w = (const float*)d_in[4];
    const float* pe_ln_b = (const float*)d_in[5];
    const float* n1_w    = (const float*)d_in[6];
    const float* n1_b    = (const float*)d_in[7];
    const float* q_w     = (const float*)d_in[8];
    const float* q_b     = (const float*)d_in[9];
    const float* kv_w    = (const float*)d_in[10];
    const float* kv_b    = (const float*)d_in[11];
    const float* rel_bias= (const float*)d_in[12];
    const float* proj_w  = (const float*)d_in[13];
    const float* proj_b  = (const float*)d_in[14];
    const float* n2_w    = (const float*)d_in[15];
    const float* n2_b    = (const float*)d_in[16];
    const float* fc1_w   = (const float*)d_in[17];
    const float* fc1_b   = (const float*)d_in[18];
    const float* fc2_w   = (const float*)d_in[19];
    const float* fc2_b   = (const float*)d_in[20];
    float* out = (float*)d_out;

    float* ws = (float*)d_ws;
    const size_t NTC = (size_t)50176 * 256;
    float* y1 = ws;                 // embed(x1); shortcut
    float* y2 = y1 + NTC;           // embed(x2); reused as yo (post-proj y)
    u16* qb   = (u16*)(y2 + NTC);
    u16* kb   = qb + NTC;
    u16* vb   = kb + NTC;
    u16* obuf = vb + NTC;
    u16* ppe  = obuf + NTC;
    u16* pq   = ppe + 65536;
    u16* pkv  = pq + 65536;
    u16* pproj= pkv + 131072;
    u16* pf1  = pproj + 65536;
    u16* pf2  = pf1 + 262144;

    pack_jt_k<<<128, 64, 0, stream>>>(pe_w,  ppe,   256, 8);   // jt-major (staged)
    pack_jt_k<<<128, 64, 0, stream>>>(q_w,   pq,    256, 8);   // jt-major (staged)
    pack_jt_k<<<256, 64, 0, stream>>>(kv_w,  pkv,   256, 8);   // jt-major (staged)
    pack_jt_k<<<128, 64, 0, stream>>>(proj_w,pproj, 256, 8);   // jt-major (staged)
    pack_jt_k<<<512, 64, 0, stream>>>(fc1_w, pf1,   256, 8);   // jt-major (staged)
    pack_k  <<<512, 64, 0, stream>>>(fc2_w, pf2,  1024, 16);   // kt-major == per-k-slice frags

    embed_k<<<dim3(784, 2), 256, 0, stream>>>(x1, x2, ppe, pe_b, pe_ln_w, pe_ln_b, y1, y2);
    qkv_k<<<784, 256, 0, stream>>>(y1, y2, n1_w, n1_b, pq, q_b, pkv, kv_b, qb, kb, vb);
    attn_k<<<dim3(1024, 2), 256, 0, stream>>>(qb, kb, vb, rel_bias, obuf);
    proj_k<<<784, 256, 0, stream>>>(obuf, pproj, proj_b, y1, y2);
    mlp_k<<<784, 256, 0, stream>>>(y2, n2_w, n2_b, pf1, fc1_b, pf2, fc2_b, out);
}

// Round 7
// 560.150 us; speedup vs baseline: 4.3204x; 1.2180x over previous
//
#include <hip/hip_runtime.h>
#include <math.h>

#define HW 3136
typedef unsigned short u16;
typedef unsigned int u32;
typedef __attribute__((ext_vector_type(8))) short bfrag;   // 8 bf16 (4 VGPRs)
typedef __attribute__((ext_vector_type(4))) float f32x4;   // MFMA accumulator

#define MFMA16(A, B, C) __builtin_amdgcn_mfma_f32_16x16x32_bf16(A, B, C, 0, 0, 0)

__device__ __forceinline__ u16 f2bf(float f) {            // RNE float->bf16
    u32 u = __builtin_bit_cast(u32, f);
    u = (u + 0x7fffu + ((u >> 16) & 1u)) >> 16;
    return (u16)u;
}
__device__ __forceinline__ float bflo(u32 v) { return __builtin_bit_cast(float, v << 16); }
__device__ __forceinline__ float bfhi(u32 v) { return __builtin_bit_cast(float, v & 0xffff0000u); }

typedef __attribute__((address_space(1))) const unsigned int g_u32;
typedef __attribute__((address_space(3))) unsigned int l_u32;
__device__ __forceinline__ void gl_lds16(const u16* g, u16* l) {
    // async global->LDS, 16B per lane; LDS dest = wave-uniform base + lane*16
    __builtin_amdgcn_global_load_lds((g_u32*)g, (l_u32*)l, 16, 0, 0);
}

// ---- all weight packs in ONE launch; jt-major (tile=jt*8+kt) except fc2 kt-major ----
__global__ void pack_all_k(
    const float* __restrict__ pe_w, const float* __restrict__ q_w,
    const float* __restrict__ kv_w, const float* __restrict__ proj_w,
    const float* __restrict__ fc1_w, const float* __restrict__ fc2_w,
    u16* __restrict__ ppe, u16* __restrict__ pq, u16* __restrict__ pkv,
    u16* __restrict__ pproj, u16* __restrict__ pf1, u16* __restrict__ pf2) {
    const int t = blockIdx.x, l = threadIdx.x;
    const float* W; u16* out; int K, tile, jt, kt;
    if (t < 128)       { W = pe_w;   out = ppe;   K = 256;  tile = t;        jt = tile / 8;  kt = tile % 8; }
    else if (t < 256)  { W = q_w;    out = pq;    K = 256;  tile = t - 128;  jt = tile / 8;  kt = tile % 8; }
    else if (t < 512)  { W = kv_w;   out = pkv;   K = 256;  tile = t - 256;  jt = tile / 8;  kt = tile % 8; }
    else if (t < 640)  { W = proj_w; out = pproj; K = 256;  tile = t - 512;  jt = tile / 8;  kt = tile % 8; }
    else if (t < 1152) { W = fc1_w;  out = pf1;   K = 256;  tile = t - 640;  jt = tile / 8;  kt = tile % 8; }
    else               { W = fc2_w;  out = pf2;   K = 1024; tile = t - 1152; kt = tile / 16; jt = tile % 16; }
    const int n = jt * 16 + (l & 15);
    const int k0 = kt * 32 + (l >> 4) * 8;
    const float* src = W + (size_t)n * K + k0;
    float4 s0 = *(const float4*)src;
    float4 s1 = *(const float4*)(src + 4);
    uint4 u;
    u.x = (u32)f2bf(s0.x) | ((u32)f2bf(s0.y) << 16);
    u.y = (u32)f2bf(s0.z) | ((u32)f2bf(s0.w) << 16);
    u.z = (u32)f2bf(s1.x) | ((u32)f2bf(s1.y) << 16);
    u.w = (u32)f2bf(s1.z) | ((u32)f2bf(s1.w) << 16);
    *(uint4*)(out + ((size_t)tile * 64 + l) * 8) = u;
}

// ---- embed: y = LN(pe_w @ x + pe_b); weights LDS-staged (dbuf), A-frags from NCHW x ----
__global__ __launch_bounds__(256) void embed_k(
    const float* __restrict__ x1, const float* __restrict__ x2,
    const u16* __restrict__ wp, const float* __restrict__ pe_b,
    const float* __restrict__ lnw, const float* __restrict__ lnb,
    float* __restrict__ y1, float* __restrict__ y2) {
    __shared__ __align__(16) u16 sh[2][8192];   // weight dbuf, 2 x 16KB (2 jt-tiles each)
    const float* x = blockIdx.y ? x2 : x1;
    float* y = blockIdx.y ? y2 : y1;
    const int tid = threadIdx.x, wv = tid >> 6, l = tid & 63;
    const int lj = l & 15, lg = l >> 4;
    const int blk = blockIdx.x, b = blk / 49;
    const int hw0 = (blk % 49) * 64 + wv * 16;     // wave's 16 tokens
    const float* xb = x + (size_t)b * 256 * HW + hw0 + lj;
    bfrag af[8];
#pragma unroll
    for (int kt = 0; kt < 8; ++kt)
#pragma unroll
        for (int bb = 0; bb < 8; ++bb)
            af[kt][bb] = (short)f2bf(xb[(size_t)(kt * 32 + lg * 8 + bb) * HW]);
    f32x4 acc[16];
#pragma unroll
    for (int jt = 0; jt < 16; ++jt) { float bb = pe_b[jt * 16 + lj]; f32x4 t = {bb, bb, bb, bb}; acc[jt] = t; }

    auto stage = [&](int c, int bufsel) {
        const u16* gsrc = wp + (size_t)c * 8192 + wv * 512 + l * 8;
        u16* dbase = &sh[bufsel][wv * 512];
#pragma unroll
        for (int r = 0; r < 4; ++r)
            gl_lds16(gsrc + r * 2048, dbase + r * 2048);
    };
    stage(0, 0);
    __syncthreads();
    int buf = 0;
#pragma unroll
    for (int c = 0; c < 8; ++c) {
        if (c < 7) stage(c + 1, buf ^ 1);
        const u16* WBb = sh[buf];
#pragma unroll
        for (int jtl = 0; jtl < 2; ++jtl) {
            const int jt = c * 2 + jtl;
#pragma unroll
            for (int kt = 0; kt < 8; ++kt)
                acc[jt] = MFMA16(af[kt], *(const bfrag*)&WBb[(jtl * 8 + kt) * 512 + l * 8], acc[jt]);
        }
        __syncthreads();
        buf ^= 1;
    }
    // LayerNorm: token row = 4*lg + r lives in this lane's 16-lane group
    float sum[4] = {0, 0, 0, 0}, sq[4] = {0, 0, 0, 0};
#pragma unroll
    for (int jt = 0; jt < 16; ++jt)
#pragma unroll
        for (int r = 0; r < 4; ++r) { float v = acc[jt][r]; sum[r] += v; sq[r] += v * v; }
#pragma unroll
    for (int r = 0; r < 4; ++r)
#pragma unroll
        for (int off = 1; off < 16; off <<= 1) { sum[r] += __shfl_xor(sum[r], off); sq[r] += __shfl_xor(sq[r], off); }
    const int p0 = b * HW + hw0;
#pragma unroll
    for (int r = 0; r < 4; ++r) {
        float mean = sum[r] * (1.f / 256.f);
        float rstd = rsqrtf(sq[r] * (1.f / 256.f) - mean * mean + 1e-5f);
        float* yrow = y + (size_t)(p0 + 4 * lg + r) * 256;
#pragma unroll
        for (int jt = 0; jt < 16; ++jt) {
            int c = jt * 16 + lj;
            yrow[c] = (acc[jt][r] - mean) * rstd * lnw[c] + lnb[c];
        }
    }
}

// ---- n1-LN + q/k/v projections; weights LDS-staged (dbuf) & shared across waves ----
__global__ __launch_bounds__(256) void qkv_k(
    const float* __restrict__ y1f, const float* __restrict__ y2f,
    const float* __restrict__ n1w, const float* __restrict__ n1b,
    const u16* __restrict__ pq, const float* __restrict__ q_b,
    const u16* __restrict__ pkv, const float* __restrict__ kv_b,
    u16* __restrict__ qb, u16* __restrict__ kb, u16* __restrict__ vb) {
    __shared__ __align__(16) u16 sh[16896];   // A-tile [64][264] ∪ weight dbuf 2×8192
    const int tid = threadIdx.x, wv = tid >> 6, l = tid & 63;
    const int lj = l & 15, lg = l >> 4;
    const int blk = blockIdx.x, b = blk / 49;
    const int hwb = (blk % 49) * 64;
    const int p0 = b * HW + hwb;
    const int row0 = wv * 16;
    u16(*A)[264] = (u16(*)[264])sh;
    const float4 nw4 = *(const float4*)&n1w[4 * l];
    const float4 nb4 = *(const float4*)&n1b[4 * l];
    bfrag af1[8], af2[8];
#pragma unroll
    for (int s = 0; s < 2; ++s) {
        const float* src = s ? y2f : y1f;
        for (int tk = 0; tk < 16; ++tk) {   // LN one token per iteration (wave-private rows)
            float4 v = *(const float4*)(src + (size_t)(p0 + row0 + tk) * 256 + 4 * l);
            float sm = v.x + v.y + v.z + v.w;
            float sq = v.x * v.x + v.y * v.y + v.z * v.z + v.w * v.w;
#pragma unroll
            for (int off = 1; off < 64; off <<= 1) { sm += __shfl_xor(sm, off); sq += __shfl_xor(sq, off); }
            float mean = sm * (1.f / 256.f);
            float rstd = rsqrtf(sq * (1.f / 256.f) - mean * mean + 1e-5f);
            float a0 = (v.x - mean) * rstd * nw4.x + nb4.x, a1 = (v.y - mean) * rstd * nw4.y + nb4.y;
            float a2 = (v.z - mean) * rstd * nw4.z + nb4.z, a3 = (v.w - mean) * rstd * nw4.w + nb4.w;
            u32* dst = (u32*)&A[row0 + tk][4 * l];
            dst[0] = (u32)f2bf(a0) | ((u32)f2bf(a1) << 16);
            dst[1] = (u32)f2bf(a2) | ((u32)f2bf(a3) << 16);
        }
        if (s == 0) {
#pragma unroll
            for (int kt = 0; kt < 8; ++kt) af1[kt] = *(const bfrag*)&A[row0 + lj][kt * 32 + lg * 8];
        } else {
#pragma unroll
            for (int kt = 0; kt < 8; ++kt) af2[kt] = *(const bfrag*)&A[row0 + lj][kt * 32 + lg * 8];
        }
    }
    int rb[4];
#pragma unroll
    for (int r = 0; r < 4; ++r) {
        int hw = hwb + row0 + 4 * lg + r;
        int hh = hw / 56, ww = hw % 56;
        int win = b * 64 + (hh / 7) * 8 + (ww / 7);
        int nn = (hh % 7) * 7 + (ww % 7);
        rb[r] = (win * 49 + nn) * 256;
    }
    __syncthreads();           // all waves done reading A before weight staging reuses it

    auto stage = [&](int c, int bufsel) {
        const u16* src = (c < 8) ? pq + (size_t)c * 8192
                       : (c < 16) ? pkv + (size_t)(c - 8) * 8192
                                  : pkv + 65536 + (size_t)(c - 16) * 8192;
        u16* dbase = sh + bufsel * 8192 + wv * 512;
        const u16* gsrc = src + wv * 512 + l * 8;
#pragma unroll
        for (int r = 0; r < 4; ++r)
            gl_lds16(gsrc + r * 2048, dbase + r * 2048);
    };
    auto do_chunk = [&](int cl, const bfrag (&af)[8], const float* bias, u16* dst, const u16* WBb) {
#pragma unroll
        for (int jtl = 0; jtl < 2; ++jtl) {
            const int jt = cl * 2 + jtl;
            float bb = bias[jt * 16 + lj];
            f32x4 acc = {bb, bb, bb, bb};
#pragma unroll
            for (int kt = 0; kt < 8; ++kt)
                acc = MFMA16(af[kt], *(const bfrag*)&WBb[(jtl * 8 + kt) * 512 + l * 8], acc);
#pragma unroll
            for (int r = 0; r < 4; ++r) dst[rb[r] + jt * 16 + lj] = f2bf(acc[r]);
        }
    };

    stage(0, 0);
    __syncthreads();
    int buf = 0;
    for (int c = 0; c < 24; ++c) {
        if (c < 23) stage(c + 1, buf ^ 1);
        const u16* WBb = sh + buf * 8192;
        if (c < 8)       do_chunk(c,      af1, q_b,        qb, WBb);
        else if (c < 16) do_chunk(c - 8,  af2, kv_b,       kb, WBb);
        else             do_chunk(c - 16, af2, kv_b + 256, vb, WBb);
        __syncthreads();
        buf ^= 1;
    }
}

// ---- attention: block = (window, 4 heads); one wave per head, barrier-free ----
__global__ __launch_bounds__(256) void attn_k(
    const u16* __restrict__ qb, const u16* __restrict__ kb, const u16* __restrict__ vb,
    const float* __restrict__ rel_bias, u16* __restrict__ ob) {
    __shared__ __align__(16) u16 ks[4][49][32];
    __shared__ __align__(16) u16 vs[4][49][32];
    __shared__ float bsh[4][169];
    const int tid = threadIdx.x, wv = tid >> 6, l = tid & 63;
    const int win = blockIdx.x;
    const int head = blockIdx.y * 4 + wv;
    const size_t wbase = (size_t)win * 49 * 256 + head * 32;
    for (int t = l; t < 196; t += 64) {       // 49 rows x 4 segs of 8 u16
        int j = t >> 2, sg = (t & 3) * 8;
        *(uint4*)&ks[wv][j][sg] = *(const uint4*)(kb + wbase + (size_t)j * 256 + sg);
        *(uint4*)&vs[wv][j][sg] = *(const uint4*)(vb + wbase + (size_t)j * 256 + sg);
    }
    for (int t = l; t < 169; t += 64) bsh[wv][t] = rel_bias[t * 8 + head];
    // no __syncthreads: all LDS regions are wave-private (in-wave lgkmcnt ordering)
    if (l < 49) {
        float qr[32];
        const uint4* qrow = (const uint4*)(qb + wbase + (size_t)l * 256);
#pragma unroll
        for (int q4 = 0; q4 < 4; ++q4) {
            uint4 u = qrow[q4];
            qr[q4 * 8 + 0] = bflo(u.x); qr[q4 * 8 + 1] = bfhi(u.x);
            qr[q4 * 8 + 2] = bflo(u.y); qr[q4 * 8 + 3] = bfhi(u.y);
            qr[q4 * 8 + 4] = bflo(u.z); qr[q4 * 8 + 5] = bfhi(u.z);
            qr[q4 * 8 + 6] = bflo(u.w); qr[q4 * 8 + 7] = bfhi(u.w);
        }
        const float scale = 0.17677669529663687f;
#pragma unroll
        for (int i = 0; i < 32; ++i) qr[i] *= scale;
        const int yi = l / 7, xi = l % 7;
        float s[49];
        float mx = -1e30f;
#pragma unroll
        for (int j = 0; j < 49; ++j) {
            float dot = 0.f;
#pragma unroll
            for (int h2 = 0; h2 < 16; ++h2) {
                u32 kk = *(const u32*)&ks[wv][j][h2 * 2];
                dot += qr[h2 * 2] * bflo(kk) + qr[h2 * 2 + 1] * bfhi(kk);
            }
            dot += bsh[wv][(yi - j / 7 + 6) * 13 + (xi - j % 7 + 6)];
            s[j] = dot;
            mx = fmaxf(mx, dot);
        }
        float denom = 0.f;
#pragma unroll
        for (int j = 0; j < 49; ++j) { float e = __expf(s[j] - mx); s[j] = e; denom += e; }
        const float inv = 1.f / denom;
        const int bwin = win >> 6, wloc = win & 63;
        const int hh = (wloc >> 3) * 7 + yi, ww = (wloc & 7) * 7 + xi;
        u16* orow = ob + ((size_t)bwin * HW + hh * 56 + ww) * 256 + head * 32;
        for (int hp = 0; hp < 16; ++hp) {
            float a0 = 0.f, a1 = 0.f;
#pragma unroll
            for (int j = 0; j < 49; ++j) {
                u32 vv = *(const u32*)&vs[wv][j][hp * 2];
                a0 += s[j] * bflo(vv); a1 += s[j] * bfhi(vv);
            }
            *(u32*)&orow[hp * 2] = (u32)f2bf(a0 * inv) | ((u32)f2bf(a1 * inv) << 16);
        }
    }
}

// ---- proj + shortcut residual: yo = y1 + o @ proj_w.T + b; weights LDS-staged (dbuf) ----
__global__ __launch_bounds__(256) void proj_k(
    const u16* __restrict__ obuf, const u16* __restrict__ pp,
    const float* __restrict__ proj_b, const float* __restrict__ y1f,
    float* __restrict__ yo) {
    __shared__ __align__(16) u16 sh[16896];   // A-tile [64][264] ∪ weight dbuf 2×8192
    const int tid = threadIdx.x, wv = tid >> 6, l = tid & 63;
    const int lj = l & 15, lg = l >> 4;
    const int blk = blockIdx.x, b = blk / 49;
    const int p0 = b * HW + (blk % 49) * 64;
    const int row0 = wv * 16;
    u16(*A)[264] = (u16(*)[264])sh;
#pragma unroll
    for (int t = 0; t < 8; ++t) {
        int rr = row0 + t * 2 + (l >> 5);
        *(uint4*)&A[rr][(l & 31) * 8] = *(const uint4*)(obuf + (size_t)(p0 + rr) * 256 + (l & 31) * 8);
    }
    bfrag af[8];
#pragma unroll
    for (int kt = 0; kt < 8; ++kt) af[kt] = *(const bfrag*)&A[row0 + lj][kt * 32 + lg * 8];
    __syncthreads();           // all waves done reading A before weight staging reuses it

    auto stage = [&](int c, int bufsel) {
        const u16* gsrc = pp + (size_t)c * 8192 + wv * 512 + l * 8;
        u16* dbase = sh + bufsel * 8192 + wv * 512;
#pragma unroll
        for (int r = 0; r < 4; ++r)
            gl_lds16(gsrc + r * 2048, dbase + r * 2048);
    };
    stage(0, 0);
    __syncthreads();
    int buf = 0;
#pragma unroll
    for (int c = 0; c < 8; ++c) {
        if (c < 7) stage(c + 1, buf ^ 1);
        const u16* WBb = sh + buf * 8192;
#pragma unroll
        for (int jtl = 0; jtl < 2; ++jtl) {
            const int jt = c * 2 + jtl;
            float bb = proj_b[jt * 16 + lj];
            f32x4 acc = {bb, bb, bb, bb};
#pragma unroll
            for (int kt = 0; kt < 8; ++kt)
                acc = MFMA16(af[kt], *(const bfrag*)&WBb[(jtl * 8 + kt) * 512 + l * 8], acc);
#pragma unroll
            for (int r = 0; r < 4; ++r) {
                size_t ad = (size_t)(p0 + row0 + 4 * lg + r) * 256 + jt * 16 + lj;
                yo[ad] = acc[r] + y1f[ad];
            }
        }
        __syncthreads();
        buf ^= 1;
    }
}

// ---- n2-LN + fc1 + GELU + fc2; 8 waves, 128 tokens/block, fc1+fc2 dbufs in dead A-tile ----
__global__ __launch_bounds__(512, 4) void mlp_k(
    const float* __restrict__ yo,
    const float* __restrict__ n2w, const float* __restrict__ n2b,
    const u16* __restrict__ pf1, const float* __restrict__ fc1_b,
    const u16* __restrict__ pf2, const float* __restrict__ fc2_b,
    float* __restrict__ out) {
    __shared__ __align__(16) u16 sh[33792];    // A[128][264] ∪ {fc1 dbuf 2x8192, fc2 dbuf 2x8192}
    __shared__ __align__(16) u16 Hs[128][36];  // GELU'd h chunk (transpose buffer)
    const int tid = threadIdx.x, wv = tid >> 6, l = tid & 63;
    const int lj = l & 15, lg = l >> 4;
    const int p0 = blockIdx.x * 128;
    const int row0 = wv * 16;
    u16(*A)[264] = (u16(*)[264])sh;
    {   // stage + n2 LayerNorm (wave-private rows)
        const float4 nw4 = *(const float4*)&n2w[4 * l];
        const float4 nb4 = *(const float4*)&n2b[4 * l];
        for (int tk = 0; tk < 16; ++tk) {
            float4 v = *(const float4*)(yo + (size_t)(p0 + row0 + tk) * 256 + 4 * l);
            float sm = v.x + v.y + v.z + v.w;
            float sq = v.x * v.x + v.y * v.y + v.z * v.z + v.w * v.w;
#pragma unroll
            for (int off = 1; off < 64; off <<= 1) { sm += __shfl_xor(sm, off); sq += __shfl_xor(sq, off); }
            float mean = sm * (1.f / 256.f);
            float rstd = rsqrtf(sq * (1.f / 256.f) - mean * mean + 1e-5f);
            float a0 = (v.x - mean) * rstd * nw4.x + nb4.x, a1 = (v.y - mean) * rstd * nw4.y + nb4.y;
            float a2 = (v.z - mean) * rstd * nw4.z + nb4.z, a3 = (v.w - mean) * rstd * nw4.w + nb4.w;
            u32* dst = (u32*)&A[row0 + tk][4 * l];
            dst[0] = (u32)f2bf(a0) | ((u32)f2bf(a1) << 16);
            dst[1] = (u32)f2bf(a2) | ((u32)f2bf(a3) << 16);
        }
    }
    bfrag af[8];    // own rows -> no barrier needed before extraction
#pragma unroll
    for (int kt = 0; kt < 8; ++kt) af[kt] = *(const bfrag*)&A[row0 + lj][kt * 32 + lg * 8];
    f32x4 acc2[16];
#pragma unroll
    for (int jt = 0; jt < 16; ++jt) acc2[jt] = *(const f32x4*)&fc2_b[jt * 16 + 4 * lg];
    __syncthreads();           // all waves done with A before dbuf staging reuses the region

    auto stage = [&](int c, int bufsel) {   // 16KB fc1 chunk + 16KB fc2 chunk, 8 waves
        const u16* g1 = pf1 + (size_t)c * 8192 + wv * 1024 + l * 8;
        u16* d1 = sh + bufsel * 8192 + wv * 1024;
        gl_lds16(g1, d1);
        gl_lds16(g1 + 512, d1 + 512);
        const u16* g2 = pf2 + (size_t)c * 8192 + wv * 1024 + l * 8;
        u16* d2 = sh + 16384 + bufsel * 8192 + wv * 1024;
        gl_lds16(g2, d2);
        gl_lds16(g2 + 512, d2 + 512);
    };

    stage(0, 0);
    __syncthreads();
    int cur = 0;
    for (int c = 0; c < 32; ++c) {
        if (c < 31) stage(c + 1, cur ^ 1);
        const u16* W1 = sh + cur * 8192;
        // fc1: 2 jt-tiles (32 h-cols) + tanh-GELU -> Hs
#pragma unroll
        for (int jtl = 0; jtl < 2; ++jtl) {
            float hb = fc1_b[c * 32 + jtl * 16 + lj];
            f32x4 a1 = {hb, hb, hb, hb};
#pragma unroll
            for (int kt = 0; kt < 8; ++kt)
                a1 = MFMA16(af[kt], *(const bfrag*)&W1[(jtl * 8 + kt) * 512 + l * 8], a1);
#pragma unroll
            for (int r = 0; r < 4; ++r) {
                float xv = a1[r];
                float uu = 0.7978845608028654f * xv * (1.0f + 0.044715f * xv * xv);
                uu = fminf(fmaxf(uu, -9.0f), 9.0f);
                float e2 = __expf(2.0f * uu);
                float g = 0.5f * xv * (1.0f + (e2 - 1.0f) / (e2 + 1.0f));
                float gn = __shfl_down(g, 1);
                if (!(l & 1))
                    *(u32*)&Hs[row0 + 4 * lg + r][jtl * 16 + (lj & 14)] = (u32)f2bf(g) | ((u32)f2bf(gn) << 16);
            }
        }
        // fc2 partial for this 32-h k-slice (swapped operands -> D[n][token])
        const u16* W2 = sh + 16384 + cur * 8192;
        bfrag hf = *(const bfrag*)&Hs[row0 + lj][lg * 8];
#pragma unroll
        for (int jt = 0; jt < 16; ++jt)
            acc2[jt] = MFMA16(*(const bfrag*)&W2[jt * 512 + l * 8], hf, acc2[jt]);
        __syncthreads();
        cur ^= 1;
    }
    // epilogue: residual gathered from token-major yo; NCHW store (per-lane token -> b,hw)
    const int t0 = p0 + row0 + lj;
    const int bb = t0 / HW, hwp = t0 % HW;
    const float* yrow = yo + (size_t)t0 * 256 + 4 * lg;
    const size_t obase = ((size_t)bb * 256) * HW + hwp;
#pragma unroll
    for (int jt = 0; jt < 16; ++jt) {
        float4 yv = *(const float4*)&yrow[jt * 16];
        const float* yp = (const float*)&yv;
#pragma unroll
        for (int r = 0; r < 4; ++r)
            out[obase + (size_t)(jt * 16 + 4 * lg + r) * HW] = yp[r] + acc2[jt][r];
    }
}

extern "C" void kernel_launch(void* const* d_in, const int* in_sizes, int n_in,
                              void* d_out, int out_size, void* d_ws, size_t ws_size,
                              hipStream_t stream) {
    const float* x1      = (const float*)d_in[0];
    const float* x2      = (const float*)d_in[1];
    const float* pe_w    = (const float*)d_in[2];
    const float* pe_b    = (const float*)d_in[3];
    const float* pe_ln_w = (const float*)d_in[4];
    const float* pe_ln_b = (const float*)d_in[5];
    const float* n1_w    = (const float*)d_in[6];
    const float* n1_b    = (const float*)d_in[7];
    const float* q_w     = (const float*)d_in[8];
    const float* q_b     = (const float*)d_in[9];
    const float* kv_w    = (const float*)d_in[10];
    const float* kv_b    = (const float*)d_in[11];
    const float* rel_bias= (const float*)d_in[12];
    const float* proj_w  = (const float*)d_in[13];
    const float* proj_b  = (const float*)d_in[14];
    const float* n2_w    = (const float*)d_in[15];
    const float* n2_b    = (const float*)d_in[16];
    const float* fc1_w   = (const float*)d_in[17];
    const float* fc1_b   = (const float*)d_in[18];
    const float* fc2_w   = (const float*)d_in[19];
    const float* fc2_b   = (const float*)d_in[20];
    float* out = (float*)d_out;

    float* ws = (float*)d_ws;
    const size_t NTC = (size_t)50176 * 256;
    float* y1 = ws;                 // embed(x1); shortcut
    float* y2 = y1 + NTC;           // embed(x2); reused as yo (post-proj y)
    u16* qb   = (u16*)(y2 + NTC);
    u16* kb   = qb + NTC;
    u16* vb   = kb + NTC;
    u16* obuf = vb + NTC;
    u16* ppe  = obuf + NTC;
    u16* pq   = ppe + 65536;
    u16* pkv  = pq + 65536;
    u16* pproj= pkv + 131072;
    u16* pf1  = pproj + 65536;
    u16* pf2  = pf1 + 262144;

    pack_all_k<<<1664, 64, 0, stream>>>(pe_w, q_w, kv_w, proj_w, fc1_w, fc2_w,
                                        ppe, pq, pkv, pproj, pf1, pf2);

    embed_k<<<dim3(784, 2), 256, 0, stream>>>(x1, x2, ppe, pe_b, pe_ln_w, pe_ln_b, y1, y2);
    qkv_k<<<784, 256, 0, stream>>>(y1, y2, n1_w, n1_b, pq, q_b, pkv, kv_b, qb, kb, vb);
    attn_k<<<dim3(1024, 2), 256, 0, stream>>>(qb, kb, vb, rel_bias, obuf);
    proj_k<<<784, 256, 0, stream>>>(obuf, pproj, proj_b, y1, y2);
    mlp_k<<<392, 512, 0, stream>>>(y2, n2_w, n2_b, pf1, fc1_b, pf2, fc2_b, out);
}

// Round 8
// 536.076 us; speedup vs baseline: 4.5144x; 1.0449x over previous
//
#include <hip/hip_runtime.h>
#include <math.h>

#define HW 3136
typedef unsigned short u16;
typedef unsigned int u32;
typedef __attribute__((ext_vector_type(8))) short bfrag;   // 8 bf16 (4 VGPRs)
typedef __attribute__((ext_vector_type(4))) float f32x4;   // MFMA accumulator

#define MFMA16(A, B, C) __builtin_amdgcn_mfma_f32_16x16x32_bf16(A, B, C, 0, 0, 0)

__device__ __forceinline__ u16 f2bf(float f) {            // RNE float->bf16
    u32 u = __builtin_bit_cast(u32, f);
    u = (u + 0x7fffu + ((u >> 16) & 1u)) >> 16;
    return (u16)u;
}
__device__ __forceinline__ float bflo(u32 v) { return __builtin_bit_cast(float, v << 16); }
__device__ __forceinline__ float bfhi(u32 v) { return __builtin_bit_cast(float, v & 0xffff0000u); }

typedef __attribute__((address_space(1))) const unsigned int g_u32;
typedef __attribute__((address_space(3))) unsigned int l_u32;
__device__ __forceinline__ void gl_lds16(const u16* g, u16* l) {
    // async global->LDS, 16B per lane; LDS dest = wave-uniform base + lane*16
    __builtin_amdgcn_global_load_lds((g_u32*)g, (l_u32*)l, 16, 0, 0);
}

// ---- all weight packs in ONE launch; jt-major (tile=jt*8+kt) except fc2 kt-major ----
__global__ void pack_all_k(
    const float* __restrict__ pe_w, const float* __restrict__ q_w,
    const float* __restrict__ kv_w, const float* __restrict__ proj_w,
    const float* __restrict__ fc1_w, const float* __restrict__ fc2_w,
    u16* __restrict__ ppe, u16* __restrict__ pq, u16* __restrict__ pkv,
    u16* __restrict__ pproj, u16* __restrict__ pf1, u16* __restrict__ pf2) {
    const int t = blockIdx.x, l = threadIdx.x;
    const float* W; u16* out; int K, tile, jt, kt;
    if (t < 128)       { W = pe_w;   out = ppe;   K = 256;  tile = t;        jt = tile / 8;  kt = tile % 8; }
    else if (t < 256)  { W = q_w;    out = pq;    K = 256;  tile = t - 128;  jt = tile / 8;  kt = tile % 8; }
    else if (t < 512)  { W = kv_w;   out = pkv;   K = 256;  tile = t - 256;  jt = tile / 8;  kt = tile % 8; }
    else if (t < 640)  { W = proj_w; out = pproj; K = 256;  tile = t - 512;  jt = tile / 8;  kt = tile % 8; }
    else if (t < 1152) { W = fc1_w;  out = pf1;   K = 256;  tile = t - 640;  jt = tile / 8;  kt = tile % 8; }
    else               { W = fc2_w;  out = pf2;   K = 1024; tile = t - 1152; kt = tile / 16; jt = tile % 16; }
    const int n = jt * 16 + (l & 15);
    const int k0 = kt * 32 + (l >> 4) * 8;
    const float* src = W + (size_t)n * K + k0;
    float4 s0 = *(const float4*)src;
    float4 s1 = *(const float4*)(src + 4);
    uint4 u;
    u.x = (u32)f2bf(s0.x) | ((u32)f2bf(s0.y) << 16);
    u.y = (u32)f2bf(s0.z) | ((u32)f2bf(s0.w) << 16);
    u.z = (u32)f2bf(s1.x) | ((u32)f2bf(s1.y) << 16);
    u.w = (u32)f2bf(s1.z) | ((u32)f2bf(s1.w) << 16);
    *(uint4*)(out + ((size_t)tile * 64 + l) * 8) = u;
}

// ---- embed: y = LN(pe_w @ x + pe_b); 8 waves, 128 tokens/block, weight dbuf staged ----
__global__ __launch_bounds__(512, 4) void embed_k(
    const float* __restrict__ x1, const float* __restrict__ x2,
    const u16* __restrict__ wp, const float* __restrict__ pe_b,
    const float* __restrict__ lnw, const float* __restrict__ lnb,
    float* __restrict__ y1, float* __restrict__ y2) {
    __shared__ __align__(16) u16 sh[2][8192];   // weight dbuf, 2 x 16KB (2 jt-tiles each)
    const float* x = blockIdx.y ? x2 : x1;
    float* y = blockIdx.y ? y2 : y1;
    const int tid = threadIdx.x, wv = tid >> 6, l = tid & 63;
    const int lj = l & 15, lg = l >> 4;
    const int t0 = blockIdx.x * 128 + wv * 16;   // wave's 16 tokens (16 | HW so no straddle)
    const int b = t0 / HW, hw0 = t0 % HW;
    const float* xb = x + (size_t)b * 256 * HW + hw0 + lj;
    bfrag af[8];
#pragma unroll
    for (int kt = 0; kt < 8; ++kt)
#pragma unroll
        for (int bb = 0; bb < 8; ++bb)
            af[kt][bb] = (short)f2bf(xb[(size_t)(kt * 32 + lg * 8 + bb) * HW]);
    f32x4 acc[16];
#pragma unroll
    for (int jt = 0; jt < 16; ++jt) { float bb = pe_b[jt * 16 + lj]; f32x4 t = {bb, bb, bb, bb}; acc[jt] = t; }

    auto stage = [&](int c, int bufsel) {      // 16KB chunk, 8 waves x 2KB
        const u16* gsrc = wp + (size_t)c * 8192 + wv * 1024 + l * 8;
        u16* dbase = &sh[bufsel][wv * 1024];
        gl_lds16(gsrc, dbase);
        gl_lds16(gsrc + 512, dbase + 512);
    };
    stage(0, 0);
    __syncthreads();
    int buf = 0;
#pragma unroll
    for (int c = 0; c < 8; ++c) {
        if (c < 7) stage(c + 1, buf ^ 1);
        const u16* WBb = sh[buf];
#pragma unroll
        for (int jtl = 0; jtl < 2; ++jtl) {
            const int jt = c * 2 + jtl;
#pragma unroll
            for (int kt = 0; kt < 8; ++kt)
                acc[jt] = MFMA16(af[kt], *(const bfrag*)&WBb[(jtl * 8 + kt) * 512 + l * 8], acc[jt]);
        }
        __syncthreads();
        buf ^= 1;
    }
    // LayerNorm: token row = 4*lg + r lives in this lane's 16-lane group
    float sum[4] = {0, 0, 0, 0}, sq[4] = {0, 0, 0, 0};
#pragma unroll
    for (int jt = 0; jt < 16; ++jt)
#pragma unroll
        for (int r = 0; r < 4; ++r) { float v = acc[jt][r]; sum[r] += v; sq[r] += v * v; }
#pragma unroll
    for (int r = 0; r < 4; ++r)
#pragma unroll
        for (int off = 1; off < 16; off <<= 1) { sum[r] += __shfl_xor(sum[r], off); sq[r] += __shfl_xor(sq[r], off); }
#pragma unroll
    for (int r = 0; r < 4; ++r) {
        float mean = sum[r] * (1.f / 256.f);
        float rstd = rsqrtf(sq[r] * (1.f / 256.f) - mean * mean + 1e-5f);
        float* yrow = y + (size_t)(t0 + 4 * lg + r) * 256;
#pragma unroll
        for (int jt = 0; jt < 16; ++jt) {
            int c = jt * 16 + lj;
            yrow[c] = (acc[jt][r] - mean) * rstd * lnw[c] + lnb[c];
        }
    }
}

// ---- n1-LN + q/k/v projections; 8 waves, 128 tokens/block; per-wave LN slabs ∪ dbuf ----
__global__ __launch_bounds__(512, 4) void qkv_k(
    const float* __restrict__ y1f, const float* __restrict__ y2f,
    const float* __restrict__ n1w, const float* __restrict__ n1b,
    const u16* __restrict__ pq, const float* __restrict__ q_b,
    const u16* __restrict__ pkv, const float* __restrict__ kv_b,
    u16* __restrict__ qb, u16* __restrict__ kb, u16* __restrict__ vb) {
    __shared__ __align__(16) u16 sh[33792];   // 8 wave-slabs [16][264] ∪ weight dbuf 2×8192
    const int tid = threadIdx.x, wv = tid >> 6, l = tid & 63;
    const int lj = l & 15, lg = l >> 4;
    const int p0 = blockIdx.x * 128;
    const int row0 = wv * 16;
    u16(*S)[264] = (u16(*)[264])(sh + wv * 4224);   // wave-private slab
    const float4 nw4 = *(const float4*)&n1w[4 * l];
    const float4 nb4 = *(const float4*)&n1b[4 * l];
    bfrag af1[8], af2[8];
#pragma unroll
    for (int s = 0; s < 2; ++s) {
        const float* src = s ? y2f : y1f;
        for (int tk = 0; tk < 16; ++tk) {   // LN one token per iteration (wave-private slab)
            float4 v = *(const float4*)(src + (size_t)(p0 + row0 + tk) * 256 + 4 * l);
            float sm = v.x + v.y + v.z + v.w;
            float sq = v.x * v.x + v.y * v.y + v.z * v.z + v.w * v.w;
#pragma unroll
            for (int off = 1; off < 64; off <<= 1) { sm += __shfl_xor(sm, off); sq += __shfl_xor(sq, off); }
            float mean = sm * (1.f / 256.f);
            float rstd = rsqrtf(sq * (1.f / 256.f) - mean * mean + 1e-5f);
            float a0 = (v.x - mean) * rstd * nw4.x + nb4.x, a1 = (v.y - mean) * rstd * nw4.y + nb4.y;
            float a2 = (v.z - mean) * rstd * nw4.z + nb4.z, a3 = (v.w - mean) * rstd * nw4.w + nb4.w;
            u32* dst = (u32*)&S[tk][4 * l];
            dst[0] = (u32)f2bf(a0) | ((u32)f2bf(a1) << 16);
            dst[1] = (u32)f2bf(a2) | ((u32)f2bf(a3) << 16);
        }
        if (s == 0) {
#pragma unroll
            for (int kt = 0; kt < 8; ++kt) af1[kt] = *(const bfrag*)&S[lj][kt * 32 + lg * 8];
        } else {
#pragma unroll
            for (int kt = 0; kt < 8; ++kt) af2[kt] = *(const bfrag*)&S[lj][kt * 32 + lg * 8];
        }
    }
    int rb[4];
#pragma unroll
    for (int r = 0; r < 4; ++r) {
        int t = p0 + row0 + 4 * lg + r;
        int b = t / HW, hw = t % HW;
        int hh = hw / 56, ww = hw % 56;
        int win = b * 64 + (hh / 7) * 8 + (ww / 7);
        int nn = (hh % 7) * 7 + (ww % 7);
        rb[r] = (win * 49 + nn) * 256;
    }
    __syncthreads();           // all waves done with slabs before dbuf staging reuses region

    auto stage = [&](int c, int bufsel) {     // 16KB chunk, 8 waves x 2KB
        const u16* src = (c < 8) ? pq + (size_t)c * 8192
                       : (c < 16) ? pkv + (size_t)(c - 8) * 8192
                                  : pkv + 65536 + (size_t)(c - 16) * 8192;
        const u16* gsrc = src + wv * 1024 + l * 8;
        u16* dbase = sh + bufsel * 8192 + wv * 1024;
        gl_lds16(gsrc, dbase);
        gl_lds16(gsrc + 512, dbase + 512);
    };
    auto do_chunk = [&](int cl, const bfrag (&af)[8], const float* bias, u16* dst, const u16* WBb) {
#pragma unroll
        for (int jtl = 0; jtl < 2; ++jtl) {
            const int jt = cl * 2 + jtl;
            float bb = bias[jt * 16 + lj];
            f32x4 acc = {bb, bb, bb, bb};
#pragma unroll
            for (int kt = 0; kt < 8; ++kt)
                acc = MFMA16(af[kt], *(const bfrag*)&WBb[(jtl * 8 + kt) * 512 + l * 8], acc);
#pragma unroll
            for (int r = 0; r < 4; ++r) dst[rb[r] + jt * 16 + lj] = f2bf(acc[r]);
        }
    };

    stage(0, 0);
    __syncthreads();
    int buf = 0;
    for (int c = 0; c < 24; ++c) {
        if (c < 23) stage(c + 1, buf ^ 1);
        const u16* WBb = sh + buf * 8192;
        if (c < 8)       do_chunk(c,      af1, q_b,        qb, WBb);
        else if (c < 16) do_chunk(c - 8,  af2, kv_b,       kb, WBb);
        else             do_chunk(c - 16, af2, kv_b + 256, vb, WBb);
        __syncthreads();
        buf ^= 1;
    }
}

// ---- attention: block = (window, 4 heads); one wave per head, barrier-free ----
__global__ __launch_bounds__(256) void attn_k(
    const u16* __restrict__ qb, const u16* __restrict__ kb, const u16* __restrict__ vb,
    const float* __restrict__ rel_bias, u16* __restrict__ ob) {
    __shared__ __align__(16) u16 ks[4][49][32];
    __shared__ __align__(16) u16 vs[4][49][32];
    __shared__ float bsh[4][169];
    const int tid = threadIdx.x, wv = tid >> 6, l = tid & 63;
    const int win = blockIdx.x;
    const int head = blockIdx.y * 4 + wv;
    const size_t wbase = (size_t)win * 49 * 256 + head * 32;
    for (int t = l; t < 196; t += 64) {       // 49 rows x 4 segs of 8 u16
        int j = t >> 2, sg = (t & 3) * 8;
        *(uint4*)&ks[wv][j][sg] = *(const uint4*)(kb + wbase + (size_t)j * 256 + sg);
        *(uint4*)&vs[wv][j][sg] = *(const uint4*)(vb + wbase + (size_t)j * 256 + sg);
    }
    for (int t = l; t < 169; t += 64) bsh[wv][t] = rel_bias[t * 8 + head];
    // no __syncthreads: all LDS regions are wave-private (in-wave lgkmcnt ordering)
    if (l < 49) {
        float qr[32];
        const uint4* qrow = (const uint4*)(qb + wbase + (size_t)l * 256);
#pragma unroll
        for (int q4 = 0; q4 < 4; ++q4) {
            uint4 u = qrow[q4];
            qr[q4 * 8 + 0] = bflo(u.x); qr[q4 * 8 + 1] = bfhi(u.x);
            qr[q4 * 8 + 2] = bflo(u.y); qr[q4 * 8 + 3] = bfhi(u.y);
            qr[q4 * 8 + 4] = bflo(u.z); qr[q4 * 8 + 5] = bfhi(u.z);
            qr[q4 * 8 + 6] = bflo(u.w); qr[q4 * 8 + 7] = bfhi(u.w);
        }
        const float scale = 0.17677669529663687f;
#pragma unroll
        for (int i = 0; i < 32; ++i) qr[i] *= scale;
        const int yi = l / 7, xi = l % 7;
        float s[49];
        float mx = -1e30f;
#pragma unroll
        for (int j = 0; j < 49; ++j) {
            float dot = 0.f;
#pragma unroll
            for (int h2 = 0; h2 < 16; ++h2) {
                u32 kk = *(const u32*)&ks[wv][j][h2 * 2];
                dot += qr[h2 * 2] * bflo(kk) + qr[h2 * 2 + 1] * bfhi(kk);
            }
            dot += bsh[wv][(yi - j / 7 + 6) * 13 + (xi - j % 7 + 6)];
            s[j] = dot;
            mx = fmaxf(mx, dot);
        }
        float denom = 0.f;
#pragma unroll
        for (int j = 0; j < 49; ++j) { float e = __expf(s[j] - mx); s[j] = e; denom += e; }
        const float inv = 1.f / denom;
        const int bwin = win >> 6, wloc = win & 63;
        const int hh = (wloc >> 3) * 7 + yi, ww = (wloc & 7) * 7 + xi;
        u16* orow = ob + ((size_t)bwin * HW + hh * 56 + ww) * 256 + head * 32;
        for (int hp = 0; hp < 16; ++hp) {
            float a0 = 0.f, a1 = 0.f;
#pragma unroll
            for (int j = 0; j < 49; ++j) {
                u32 vv = *(const u32*)&vs[wv][j][hp * 2];
                a0 += s[j] * bflo(vv); a1 += s[j] * bfhi(vv);
            }
            *(u32*)&orow[hp * 2] = (u32)f2bf(a0 * inv) | ((u32)f2bf(a1 * inv) << 16);
        }
    }
}

// ---- proj + shortcut residual; 8 waves, 128 tokens/block; per-wave A slabs ∪ dbuf ----
__global__ __launch_bounds__(512, 4) void proj_k(
    const u16* __restrict__ obuf, const u16* __restrict__ pp,
    const float* __restrict__ proj_b, const float* __restrict__ y1f,
    float* __restrict__ yo) {
    __shared__ __align__(16) u16 sh[33792];   // 8 wave-slabs [16][264] ∪ weight dbuf 2×8192
    const int tid = threadIdx.x, wv = tid >> 6, l = tid & 63;
    const int lj = l & 15, lg = l >> 4;
    const int p0 = blockIdx.x * 128;
    const int row0 = wv * 16;
    u16(*S)[264] = (u16(*)[264])(sh + wv * 4224);
#pragma unroll
    for (int t = 0; t < 8; ++t) {
        int rr = t * 2 + (l >> 5);
        *(uint4*)&S[rr][(l & 31) * 8] = *(const uint4*)(obuf + (size_t)(p0 + row0 + rr) * 256 + (l & 31) * 8);
    }
    bfrag af[8];
#pragma unroll
    for (int kt = 0; kt < 8; ++kt) af[kt] = *(const bfrag*)&S[lj][kt * 32 + lg * 8];
    __syncthreads();           // all waves done with slabs before dbuf staging reuses region

    auto stage = [&](int c, int bufsel) {
        const u16* gsrc = pp + (size_t)c * 8192 + wv * 1024 + l * 8;
        u16* dbase = sh + bufsel * 8192 + wv * 1024;
        gl_lds16(gsrc, dbase);
        gl_lds16(gsrc + 512, dbase + 512);
    };
    stage(0, 0);
    __syncthreads();
    int buf = 0;
#pragma unroll
    for (int c = 0; c < 8; ++c) {
        if (c < 7) stage(c + 1, buf ^ 1);
        const u16* WBb = sh + buf * 8192;
#pragma unroll
        for (int jtl = 0; jtl < 2; ++jtl) {
            const int jt = c * 2 + jtl;
            float bb = proj_b[jt * 16 + lj];
            f32x4 acc = {bb, bb, bb, bb};
#pragma unroll
            for (int kt = 0; kt < 8; ++kt)
                acc = MFMA16(af[kt], *(const bfrag*)&WBb[(jtl * 8 + kt) * 512 + l * 8], acc);
#pragma unroll
            for (int r = 0; r < 4; ++r) {
                size_t ad = (size_t)(p0 + row0 + 4 * lg + r) * 256 + jt * 16 + lj;
                yo[ad] = acc[r] + y1f[ad];
            }
        }
        __syncthreads();
        buf ^= 1;
    }
}

// ---- n2-LN + fc1 + GELU + fc2; 8 waves, 128 tokens/block, fc1+fc2 dbufs in dead A-tile ----
__global__ __launch_bounds__(512, 4) void mlp_k(
    const float* __restrict__ yo,
    const float* __restrict__ n2w, const float* __restrict__ n2b,
    const u16* __restrict__ pf1, const float* __restrict__ fc1_b,
    const u16* __restrict__ pf2, const float* __restrict__ fc2_b,
    float* __restrict__ out) {
    __shared__ __align__(16) u16 sh[33792];    // A[128][264] ∪ {fc1 dbuf 2x8192, fc2 dbuf 2x8192}
    __shared__ __align__(16) u16 Hs[128][36];  // GELU'd h chunk (transpose buffer)
    const int tid = threadIdx.x, wv = tid >> 6, l = tid & 63;
    const int lj = l & 15, lg = l >> 4;
    const int p0 = blockIdx.x * 128;
    const int row0 = wv * 16;
    u16(*A)[264] = (u16(*)[264])sh;
    {   // stage + n2 LayerNorm (wave-private rows)
        const float4 nw4 = *(const float4*)&n2w[4 * l];
        const float4 nb4 = *(const float4*)&n2b[4 * l];
        for (int tk = 0; tk < 16; ++tk) {
            float4 v = *(const float4*)(yo + (size_t)(p0 + row0 + tk) * 256 + 4 * l);
            float sm = v.x + v.y + v.z + v.w;
            float sq = v.x * v.x + v.y * v.y + v.z * v.z + v.w * v.w;
#pragma unroll
            for (int off = 1; off < 64; off <<= 1) { sm += __shfl_xor(sm, off); sq += __shfl_xor(sq, off); }
            float mean = sm * (1.f / 256.f);
            float rstd = rsqrtf(sq * (1.f / 256.f) - mean * mean + 1e-5f);
            float a0 = (v.x - mean) * rstd * nw4.x + nb4.x, a1 = (v.y - mean) * rstd * nw4.y + nb4.y;
            float a2 = (v.z - mean) * rstd * nw4.z + nb4.z, a3 = (v.w - mean) * rstd * nw4.w + nb4.w;
            u32* dst = (u32*)&A[row0 + tk][4 * l];
            dst[0] = (u32)f2bf(a0) | ((u32)f2bf(a1) << 16);
            dst[1] = (u32)f2bf(a2) | ((u32)f2bf(a3) << 16);
        }
    }
    bfrag af[8];    // own rows -> no barrier needed before extraction
#pragma unroll
    for (int kt = 0; kt < 8; ++kt) af[kt] = *(const bfrag*)&A[row0 + lj][kt * 32 + lg * 8];
    f32x4 acc2[16];
#pragma unroll
    for (int jt = 0; jt < 16; ++jt) acc2[jt] = *(const f32x4*)&fc2_b[jt * 16 + 4 * lg];
    __syncthreads();           // all waves done with A before dbuf staging reuses the region

    auto stage = [&](int c, int bufsel) {   // 16KB fc1 chunk + 16KB fc2 chunk, 8 waves
        const u16* g1 = pf1 + (size_t)c * 8192 + wv * 1024 + l * 8;
        u16* d1 = sh + bufsel * 8192 + wv * 1024;
        gl_lds16(g1, d1);
        gl_lds16(g1 + 512, d1 + 512);
        const u16* g2 = pf2 + (size_t)c * 8192 + wv * 1024 + l * 8;
        u16* d2 = sh + 16384 + bufsel * 8192 + wv * 1024;
        gl_lds16(g2, d2);
        gl_lds16(g2 + 512, d2 + 512);
    };

    stage(0, 0);
    __syncthreads();
    int cur = 0;
    for (int c = 0; c < 32; ++c) {
        if (c < 31) stage(c + 1, cur ^ 1);
        const u16* W1 = sh + cur * 8192;
        // fc1: 2 jt-tiles (32 h-cols) + tanh-GELU -> Hs
#pragma unroll
        for (int jtl = 0; jtl < 2; ++jtl) {
            float hb = fc1_b[c * 32 + jtl * 16 + lj];
            f32x4 a1 = {hb, hb, hb, hb};
#pragma unroll
            for (int kt = 0; kt < 8; ++kt)
                a1 = MFMA16(af[kt], *(const bfrag*)&W1[(jtl * 8 + kt) * 512 + l * 8], a1);
#pragma unroll
            for (int r = 0; r < 4; ++r) {
                float xv = a1[r];
                float uu = 0.7978845608028654f * xv * (1.0f + 0.044715f * xv * xv);
                uu = fminf(fmaxf(uu, -9.0f), 9.0f);
                float e2 = __expf(2.0f * uu);
                float g = 0.5f * xv * (1.0f + (e2 - 1.0f) / (e2 + 1.0f));
                float gn = __shfl_down(g, 1);
                if (!(l & 1))
                    *(u32*)&Hs[row0 + 4 * lg + r][jtl * 16 + (lj & 14)] = (u32)f2bf(g) | ((u32)f2bf(gn) << 16);
            }
        }
        // fc2 partial for this 32-h k-slice (swapped operands -> D[n][token])
        const u16* W2 = sh + 16384 + cur * 8192;
        bfrag hf = *(const bfrag*)&Hs[row0 + lj][lg * 8];
#pragma unroll
        for (int jt = 0; jt < 16; ++jt)
            acc2[jt] = MFMA16(*(const bfrag*)&W2[jt * 512 + l * 8], hf, acc2[jt]);
        __syncthreads();
        cur ^= 1;
    }
    // epilogue: residual gathered from token-major yo; NCHW store (per-lane token -> b,hw)
    const int t0 = p0 + row0 + lj;
    const int bb = t0 / HW, hwp = t0 % HW;
    const float* yrow = yo + (size_t)t0 * 256 + 4 * lg;
    const size_t obase = ((size_t)bb * 256) * HW + hwp;
#pragma unroll
    for (int jt = 0; jt < 16; ++jt) {
        float4 yv = *(const float4*)&yrow[jt * 16];
        const float* yp = (const float*)&yv;
#pragma unroll
        for (int r = 0; r < 4; ++r)
            out[obase + (size_t)(jt * 16 + 4 * lg + r) * HW] = yp[r] + acc2[jt][r];
    }
}

extern "C" void kernel_launch(void* const* d_in, const int* in_sizes, int n_in,
                              void* d_out, int out_size, void* d_ws, size_t ws_size,
                              hipStream_t stream) {
    const float* x1      = (const float*)d_in[0];
    const float* x2      = (const float*)d_in[1];
    const float* pe_w    = (const float*)d_in[2];
    const float* pe_b    = (const float*)d_in[3];
    const float* pe_ln_w = (const float*)d_in[4];
    const float* pe_ln_b = (const float*)d_in[5];
    const float* n1_w    = (const float*)d_in[6];
    const float* n1_b    = (const float*)d_in[7];
    const float* q_w     = (const float*)d_in[8];
    const float* q_b     = (const float*)d_in[9];
    const float* kv_w    = (const float*)d_in[10];
    const float* kv_b    = (const float*)d_in[11];
    const float* rel_bias= (const float*)d_in[12];
    const float* proj_w  = (const float*)d_in[13];
    const float* proj_b  = (const float*)d_in[14];
    const float* n2_w    = (const float*)d_in[15];
    const float* n2_b    = (const float*)d_in[16];
    const float* fc1_w   = (const float*)d_in[17];
    const float* fc1_b   = (const float*)d_in[18];
    const float* fc2_w   = (const float*)d_in[19];
    const float* fc2_b   = (const float*)d_in[20];
    float* out = (float*)d_out;

    float* ws = (float*)d_ws;
    const size_t NTC = (size_t)50176 * 256;
    float* y1 = ws;                 // embed(x1); shortcut
    float* y2 = y1 + NTC;           // embed(x2); reused as yo (post-proj y)
    u16* qb   = (u16*)(y2 + NTC);
    u16* kb   = qb + NTC;
    u16* vb   = kb + NTC;
    u16* obuf = vb + NTC;
    u16* ppe  = obuf + NTC;
    u16* pq   = ppe + 65536;
    u16* pkv  = pq + 65536;
    u16* pproj= pkv + 131072;
    u16* pf1  = pproj + 65536;
    u16* pf2  = pf1 + 262144;

    pack_all_k<<<1664, 64, 0, stream>>>(pe_w, q_w, kv_w, proj_w, fc1_w, fc2_w,
                                        ppe, pq, pkv, pproj, pf1, pf2);

    embed_k<<<dim3(392, 2), 512, 0, stream>>>(x1, x2, ppe, pe_b, pe_ln_w, pe_ln_b, y1, y2);
    qkv_k<<<392, 512, 0, stream>>>(y1, y2, n1_w, n1_b, pq, q_b, pkv, kv_b, qb, kb, vb);
    attn_k<<<dim3(1024, 2), 256, 0, stream>>>(qb, kb, vb, rel_bias, obuf);
    proj_k<<<392, 512, 0, stream>>>(obuf, pproj, proj_b, y1, y2);
    mlp_k<<<392, 512, 0, stream>>>(y2, n2_w, n2_b, pf1, fc1_b, pf2, fc2_b, out);
}